// Round 1
// baseline (422.411 us; speedup 1.0000x reference)
//
#include <hip/hip_runtime.h>
#include <hip/hip_bf16.h>
#include <math.h>

#define BB 2
#define NPIX 131072            // 2*256*256

// ws float header (4-slot accumulators)
#define WS_G    0              // [slot4][B][1024]  (G[c=h*16+d][e])
#define WS_SSQ  8192           // [slot4][2][B][64] (0=q,1=k)
#define WS_M    9216           // [B][4096] folded Wp*blockdiag(attn), transposed
#define WS_WSWZ_BYTE ((size_t)17408*4)            // 20480 ushort pre-swizzled weights (40 KB)
#define WS_M2_BYTE   (WS_WSWZ_BYTE + 40960)       // m2 bf16: NPIX*64*2 = 16.78 MB

typedef __attribute__((ext_vector_type(8))) short short8;
typedef __attribute__((ext_vector_type(4))) float f32x4;

__device__ __forceinline__ unsigned short f2bf(float f) {
    unsigned u = __float_as_uint(f);
    u += 0x7FFFu + ((u >> 16) & 1u);            // RNE
    return (unsigned short)(u >> 16);
}
__device__ __forceinline__ float bf2f(unsigned short s) {
    return __uint_as_float((unsigned)s << 16);
}
__device__ __forceinline__ void lds_fence() {
    __asm__ __volatile__("s_waitcnt lgkmcnt(0)" ::: "memory");
}

// ---------------------------------------------------------------------------
// K0: pre-swizzle the 5 weight matrices into MFMA B-frag order, bf16, in ws.
// frag f = matot*2+kh; element (f, lane l, j) = W[ot*16+(l&15)][kh*32+((l>>4)&3)*8+j]
// ---------------------------------------------------------------------------
__global__ __launch_bounds__(256) void k_prep(const float* __restrict__ Wq,
    const float* __restrict__ Wk, const float* __restrict__ Wv,
    const float* __restrict__ w1, const float* __restrict__ w2,
    unsigned short* __restrict__ wg)
{
    const int i = blockIdx.x*256 + threadIdx.x;     // 80 blocks -> 20480
    const int f = i >> 9, l = (i >> 3) & 63, j = i & 7;
    const int matot = f >> 1, kh = f & 1;
    const int mat = matot >> 2, ot = matot & 3;
    const int o = ot*16 + (l & 15);
    const int cc = kh*32 + ((l >> 4) & 3)*8 + j;
    const float* Wsrc[5] = {Wq, Wk, Wv, w1, w2};
    wg[i] = f2bf(Wsrc[mat][o*64 + cc]);
}

// ---------------------------------------------------------------------------
// K1 (MFMA, fused): per 128-px block (1024 blocks, 4/CU resident):
//   q,k,v = x@{Wq,Wk,Wv}^T ; m1 = mask@w1^T+b1 ; vm0 = v*m1 -> d_out (fp32);
//   m2 = m1@w2^T+b2 -> ws bf16 ; Gram G + ssq -> 4-slot atomics.
// Weights: B-frags read DIRECTLY from global wg (pre-swizzled, per-lane 16B
// contiguous -> one global_load_dwordx4 each; same 40KB shared by all waves
// -> L1/L2 resident). No weight LDS => LDS = 17 + 2 = 19.5 KB.
// Occupancy: VGPR-capped at 128 (launch_bounds 256,4) -> 4 blocks/CU,
// 16 waves/CU (was 2 blocks / 8 waves with the 40KB LDS weight buffer).
// ---------------------------------------------------------------------------
__global__ __launch_bounds__(256, 4) void k_fused(
    const float* __restrict__ x, const float* __restrict__ mask,
    const unsigned short* __restrict__ wg,
    const float* __restrict__ b1, const float* __restrict__ b2,
    float* __restrict__ ws, float* __restrict__ out,
    __hip_bfloat16* __restrict__ m2out)
{
    __shared__ unsigned short scr[4][2176];         // 4.25 KB per wave
    __shared__ float s_ssq[4][2][64];               // 2 KB
    const int tid = threadIdx.x, lane = tid & 63, w = tid >> 6;
    const int quad = lane >> 4, col = lane & 15;
    const int blk = blockIdx.x, b = blk >> 9, slot = blk & 3;

    float b1v[4], b2v[4];
#pragma unroll
    for (int ot = 0; ot < 4; ++ot) {
        b1v[ot] = b1[ot*16 + col];
        b2v[ot] = b2[ot*16 + col];
    }

#define WFRAG(matot, kh) (*(const short8*)&wg[(((matot)*2 + (kh))*64 + lane)*8])

    float accG[16];
#pragma unroll
    for (int e = 0; e < 16; ++e) accG[e] = 0.f;
    float ssq_q = 0.f, ssq_k = 0.f;
    const int hbase = lane & 48;
    unsigned short* S = scr[w];

    for (int t = 0; t < 2; ++t) {
        const int pbase = blk*128 + t*64 + w*16;

        // A-frags from global (fp32 -> bf16): A[m=col(px)][k=quad*8+j (+32kh)]
        short8 xA[2], mA[2];
        {
            const float* xs = x    + ((size_t)(pbase + col))*64 + quad*8;
            const float* ms = mask + ((size_t)(pbase + col))*64 + quad*8;
#pragma unroll
            for (int kh = 0; kh < 2; ++kh) {
                float4 a0 = *(const float4*)(xs + kh*32);
                float4 a1 = *(const float4*)(xs + kh*32 + 4);
                float4 b0 = *(const float4*)(ms + kh*32);
                float4 b1f = *(const float4*)(ms + kh*32 + 4);
#pragma unroll
                for (int j = 0; j < 4; ++j) {
                    xA[kh][j]   = (short)f2bf((&a0.x)[j]);
                    xA[kh][4+j] = (short)f2bf((&a1.x)[j]);
                    mA[kh][j]   = (short)f2bf((&b0.x)[j]);
                    mA[kh][4+j] = (short)f2bf((&b1f.x)[j]);
                }
            }
        }

        // Phase A: q,k -> S as ushort [mat][p][68]
#pragma unroll
        for (int mm = 0; mm < 2; ++mm) {
#pragma unroll
            for (int ot = 0; ot < 4; ++ot) {
                f32x4 a = {0.f, 0.f, 0.f, 0.f};
                a = __builtin_amdgcn_mfma_f32_16x16x32_bf16(xA[0], WFRAG(mm*4+ot,0), a, 0,0,0);
                a = __builtin_amdgcn_mfma_f32_16x16x32_bf16(xA[1], WFRAG(mm*4+ot,1), a, 0,0,0);
#pragma unroll
                for (int r = 0; r < 4; ++r)
                    S[mm*1088 + (quad*4+r)*68 + ot*16 + col] = f2bf(a[r]);
            }
        }
        __builtin_amdgcn_wave_barrier();
        // Gram + ssq (lane = channel c): G[c][e] += k[p][c]*q[p][(c&48)+e]
#pragma unroll
        for (int p = 0; p < 16; ++p) {
            const float kv = bf2f(S[1088 + p*68 + lane]);
            const float qo = bf2f(S[p*68 + lane]);
            ssq_k = fmaf(kv, kv, ssq_k);
            ssq_q = fmaf(qo, qo, ssq_q);
#pragma unroll
            for (int e4 = 0; e4 < 4; ++e4) {
                ushort4 qq = *(const ushort4*)&S[p*68 + hbase + e4*4];
                accG[e4*4+0] = fmaf(kv, bf2f(qq.x), accG[e4*4+0]);
                accG[e4*4+1] = fmaf(kv, bf2f(qq.y), accG[e4*4+1]);
                accG[e4*4+2] = fmaf(kv, bf2f(qq.z), accG[e4*4+2]);
                accG[e4*4+3] = fmaf(kv, bf2f(qq.w), accG[e4*4+3]);
            }
        }
        lds_fence();                    // Gram reads done before S reused

        // v, m1
        f32x4 vfr[4], m1fr[4];
#pragma unroll
        for (int ot = 0; ot < 4; ++ot) {
            f32x4 a = {0.f, 0.f, 0.f, 0.f};
            a = __builtin_amdgcn_mfma_f32_16x16x32_bf16(xA[0], WFRAG(8+ot,0), a, 0,0,0);
            a = __builtin_amdgcn_mfma_f32_16x16x32_bf16(xA[1], WFRAG(8+ot,1), a, 0,0,0);
            vfr[ot] = a;
        }
#pragma unroll
        for (int ot = 0; ot < 4; ++ot) {
            f32x4 a = {0.f, 0.f, 0.f, 0.f};
            a = __builtin_amdgcn_mfma_f32_16x16x32_bf16(mA[0], WFRAG(12+ot,0), a, 0,0,0);
            a = __builtin_amdgcn_mfma_f32_16x16x32_bf16(mA[1], WFRAG(12+ot,1), a, 0,0,0);
#pragma unroll
            for (int r = 0; r < 4; ++r) a[r] += b1v[ot];
            m1fr[ot] = a;
        }

        // Phase B: vm0 fp32 [16][66] in S, then coalesced 512B row stores
        float* vscr = (float*)S;
#pragma unroll
        for (int ot = 0; ot < 4; ++ot)
#pragma unroll
            for (int r = 0; r < 4; ++r)
                vscr[(quad*4+r)*66 + ot*16 + col] = vfr[ot][r] * m1fr[ot][r];
        __builtin_amdgcn_wave_barrier();
        {
            const int rb = lane >> 5, ci = (lane & 31)*2;
#pragma unroll
            for (int pp = 0; pp < 8; ++pp) {
                const int row = pp*2 + rb;
                float2 v2 = *(const float2*)&vscr[row*66 + ci];
                *(float2*)&out[((size_t)(pbase + row))*64 + ci] = v2;
            }
        }
        lds_fence();                    // vm0 reads done before S reused

        // Phase C: m1 bf16 [16][72] in S -> A-frags for m2
#pragma unroll
        for (int ot = 0; ot < 4; ++ot)
#pragma unroll
            for (int r = 0; r < 4; ++r)
                S[(quad*4+r)*72 + ot*16 + col] = f2bf(m1fr[ot][r]);
        __builtin_amdgcn_wave_barrier();
        short8 a2[2];
#pragma unroll
        for (int kh = 0; kh < 2; ++kh)
            a2[kh] = *(const short8*)&S[col*72 + kh*32 + quad*8];
        lds_fence();                    // a2 reads done before S overwritten

        // Phase D: m2 mfma, bf16 [16][72] in S, coalesced packed-uint stores
#pragma unroll
        for (int ot = 0; ot < 4; ++ot) {
            f32x4 a = {0.f, 0.f, 0.f, 0.f};
            a = __builtin_amdgcn_mfma_f32_16x16x32_bf16(a2[0], WFRAG(16+ot,0), a, 0,0,0);
            a = __builtin_amdgcn_mfma_f32_16x16x32_bf16(a2[1], WFRAG(16+ot,1), a, 0,0,0);
#pragma unroll
            for (int r = 0; r < 4; ++r)
                S[(quad*4+r)*72 + ot*16 + col] = f2bf(a[r] + b2v[ot]);
        }
        __builtin_amdgcn_wave_barrier();
        {
            unsigned short* m2u = (unsigned short*)m2out;
            const int rb = lane >> 5, ci = (lane & 31)*2;
#pragma unroll
            for (int pp = 0; pp < 8; ++pp) {
                const int row = pp*2 + rb;
                unsigned vv = *(const unsigned*)&S[row*72 + ci];
                *(unsigned*)&m2u[((size_t)(pbase + row))*64 + ci] = vv;
            }
        }
        lds_fence();                    // m2 reads done before next iter
    }

    __syncthreads();                    // all waves done with scr

    // two-phase block reduction of G (2048 floats in scr), layout [w2][e][lane]
    float* gr = (float*)&scr[0][0];
    if (w < 2) {
#pragma unroll
        for (int e = 0; e < 16; ++e) gr[w*1024 + e*64 + lane] = accG[e];
    }
    s_ssq[w][0][lane] = ssq_q;
    s_ssq[w][1][lane] = ssq_k;
    __syncthreads();
    if (w >= 2) {
#pragma unroll
        for (int e = 0; e < 16; ++e) gr[(w-2)*1024 + e*64 + lane] += accG[e];
    }
    __syncthreads();
    float* Gg = ws + WS_G + (size_t)slot*2048 + (size_t)b*1024;
    for (int idx = tid; idx < 1024; idx += 256) {
        const int e = idx >> 6, c = idx & 63;
        atomicAdd(&Gg[c*16 + e], gr[idx] + gr[1024 + idx]);
    }
    if (tid < 128) {
        const int which = tid >> 6, cidx = tid & 63;
        float s = s_ssq[0][which][cidx] + s_ssq[1][which][cidx]
                + s_ssq[2][which][cidx] + s_ssq[3][which][cidx];
        atomicAdd(ws + WS_SSQ + (size_t)slot*256 + which*128 + b*64 + cidx, s);
    }
#undef WFRAG
}

// ---------------------------------------------------------------------------
// K2: softmax over normalized Gram (sum 4 slots), folded with Wp:
//   Mt[b][c=h*16+e][o] = sum_d Wp[o][h*16+d] * attn[b][h][d][e].  2 blocks.
// ---------------------------------------------------------------------------
__global__ __launch_bounds__(256) void k_attn(const float* __restrict__ rescale,
    const float* __restrict__ Wp, float* __restrict__ ws)
{
    __shared__ float sAtt[1024];        // [h][d][e]
    const int b = blockIdx.x, t = threadIdx.x;
    const int d = t >> 4, e = t & 15;
#pragma unroll
    for (int h = 0; h < 4; ++h) {
        float g = 0.f, nk2 = 0.f, nq2 = 0.f;
#pragma unroll
        for (int s = 0; s < 4; ++s) {
            g   += ws[WS_G + s*2048 + b*1024 + (h*16+d)*16 + e];
            nk2 += ws[WS_SSQ + s*256 + 128 + b*64 + h*16 + d];
            nq2 += ws[WS_SSQ + s*256 +   0 + b*64 + h*16 + e];
        }
        float nk = fmaxf(sqrtf(nk2), 1e-12f);
        float nq = fmaxf(sqrtf(nq2), 1e-12f);
        float val = g / (nk*nq) * rescale[h];
        float m = val;
        for (int off = 1; off < 16; off <<= 1) m = fmaxf(m, __shfl_xor(m, off, 16));
        float ev = expf(val - m);
        float s2 = ev;
        for (int off = 1; off < 16; off <<= 1) s2 += __shfl_xor(s2, off, 16);
        sAtt[h*256 + d*16 + e] = ev / s2;
    }
    __syncthreads();
    float* Mtb = ws + WS_M + (size_t)b*4096;
    for (int idx = t; idx < 4096; idx += 256) {
        const int c = idx >> 6, o = idx & 63, h = c >> 4, ee = c & 15;
        float acc = 0.f;
#pragma unroll
        for (int d2 = 0; d2 < 16; ++d2)
            acc = fmaf(Wp[o*64 + h*16 + d2], sAtt[h*256 + d2*16 + ee], acc);
        Mtb[c*64 + o] = acc;
    }
}

// ---------------------------------------------------------------------------
// K3: per 8x8 tile: dwconv5x5(m2 bf16 halo)+dwb -> sigmoid ->
//   vm = vm0(d_out)*(1+sig) -> out = Mt . vm + bp.
// ---------------------------------------------------------------------------
__global__ __launch_bounds__(256, 4) void k_final(
    const __hip_bfloat16* __restrict__ m2g, const float* __restrict__ wsM,
    const float* __restrict__ bp, const float* __restrict__ dw,
    const float* __restrict__ dwb, float* __restrict__ out)
{
    __shared__ unsigned short m2s[144*64];  // 18.4 KB bf16 halo (0 outside)
    __shared__ unsigned short Mtl[4096];    // 8 KB bf16 blocked-f4 [c4][o][u]
    __shared__ float s_vm[4][4][64];        // per-wave
    const int tid = threadIdx.x, lane = tid & 63, w = tid >> 6;
    const int bid = blockIdx.x;
    const int b = bid >> 10, tile = bid & 1023;
    const int y0 = (tile >> 5) * 8, x0 = (tile & 31) * 8;
    const int c = lane;

    const float* Msrc = wsM + (size_t)b*4096;
    for (int i = tid; i < 4096; i += 256) {
        const int o = (i >> 2) & 63, gc = (i >> 8) * 4 + (i & 3);
        Mtl[i] = f2bf(Msrc[gc*64 + o]);
    }
    for (int i2 = tid; i2 < 2304; i2 += 256) {
        const int pos = i2 >> 4, c4 = (i2 & 15) * 4;
        const int yy = pos / 12, xx = pos - yy*12;
        const int gy = y0 + yy - 2, gx = x0 + xx - 2;
        ushort4 us = make_ushort4(0, 0, 0, 0);
        if (gy >= 0 && gy < 256 && gx >= 0 && gx < 256)
            us = *(const ushort4*)&m2g[(((size_t)b*256 + gy)*256 + gx)*64 + c4];
        *(ushort4*)&m2s[pos*64 + c4] = us;
    }
    __syncthreads();

    const float dwbr = dwb[c], bpr = bp[c];
    float dwr[25];
#pragma unroll
    for (int k = 0; k < 25; ++k) dwr[k] = dw[c*25+k];

    for (int g = 0; g < 4; ++g) {
        const int p0 = w*16 + g*4;          // 4 consecutive px in one row
        const int py = p0 >> 3, px0 = p0 & 7;
        float acc[4] = {dwbr, dwbr, dwbr, dwbr};
#pragma unroll
        for (int ky = 0; ky < 5; ++ky) {
            const int rbase = ((py+ky)*12 + px0)*64 + c;
#pragma unroll
            for (int kx8 = 0; kx8 < 8; ++kx8) {
                const float tv = bf2f(m2s[rbase + kx8*64]);
#pragma unroll
                for (int j = 0; j < 4; ++j) {
                    const int kk = kx8 - j;
                    if (kk >= 0 && kk < 5)
                        acc[j] = fmaf(tv, dwr[ky*5 + kk], acc[j]);
                }
            }
        }
        size_t P[4];
#pragma unroll
        for (int j = 0; j < 4; ++j) {
            P[j] = (size_t)b*65536 + (size_t)(y0+py)*256 + (x0+px0+j);
            const float s = 1.f / (1.f + expf(-acc[j]));
            s_vm[w][j][c] = out[P[j]*64 + c] * (1.f + s);   // vm0 * (1+sig)
        }
        __builtin_amdgcn_wave_barrier();
        float oc[4] = {bpr, bpr, bpr, bpr};
        for (int c4 = 0; c4 < 16; ++c4) {
            float4 v4[4];
#pragma unroll
            for (int j = 0; j < 4; ++j)
                v4[j] = *(const float4*)&s_vm[w][j][c4*4];  // broadcast
            const ushort4 m4 = *(const ushort4*)&Mtl[c4*256 + lane*4];
            const float mf[4] = {bf2f(m4.x), bf2f(m4.y), bf2f(m4.z), bf2f(m4.w)};
#pragma unroll
            for (int u = 0; u < 4; ++u)
#pragma unroll
                for (int j = 0; j < 4; ++j)
                    oc[j] = fmaf((&v4[j].x)[u], mf[u], oc[j]);
        }
#pragma unroll
        for (int j = 0; j < 4; ++j)
            out[P[j]*64 + c] = oc[j];
        __builtin_amdgcn_wave_barrier();
    }
}

// ---------------------------------------------------------------------------
// K4 (last): PE branch dwconv3x3 -> gelu -> dwconv3x3, += d_out.
// xt and t1 bf16 in LDS; t1 outside image is ZERO (conv2 padding).
// ---------------------------------------------------------------------------
__global__ __launch_bounds__(256, 5) void k_pe(const float* __restrict__ x,
    const float* __restrict__ w1, const float* __restrict__ w2,
    float* __restrict__ out)
{
    __shared__ unsigned short xt[12*12*64];     // 18.4 KB bf16
    __shared__ unsigned short t1[10*10*64];     // 12.8 KB bf16
    const int tid = threadIdx.x;
    const int bid = blockIdx.x;
    const int b = bid >> 10, tile = bid & 1023;
    const int y0 = (tile >> 5) * 8, x0 = (tile & 31) * 8;
    const int c = tid & 63;
    float w1r[9], w2r[9];
#pragma unroll
    for (int k = 0; k < 9; ++k) { w1r[k] = w1[c*9+k]; w2r[k] = w2[c*9+k]; }

    for (int i = tid; i < 12*12*64; i += 256) {
        int yy = i / 768, xx = (i % 768) >> 6;
        int gy = y0 + yy - 2, gx = x0 + xx - 2;
        float v = 0.f;
        if (gy >= 0 && gy < 256 && gx >= 0 && gx < 256)
            v = x[(((size_t)b*256 + gy)*256 + gx)*64 + c];
        xt[i] = f2bf(v);
    }
    __syncthreads();
    for (int i = tid; i < 10*10*64; i += 256) {
        int yy = i / 640, xx = (i % 640) >> 6;
        int gy = y0 + yy - 1, gx = x0 + xx - 1;
        float val = 0.f;
        if (gy >= 0 && gy < 256 && gx >= 0 && gx < 256) {
            float acc = 0.f;
#pragma unroll
            for (int ky = 0; ky < 3; ++ky)
#pragma unroll
                for (int kx = 0; kx < 3; ++kx)
                    acc = fmaf(bf2f(xt[((yy+ky)*12 + xx+kx)*64 + c]),
                               w1r[ky*3+kx], acc);
            val = 0.5f * acc * (1.f + erff(acc * 0.70710678118654752f));
        }
        t1[i] = f2bf(val);
    }
    __syncthreads();
    for (int i = tid; i < 8*8*64; i += 256) {
        int yy = i / 512, xx = (i % 512) >> 6;
        float acc = 0.f;
#pragma unroll
        for (int ky = 0; ky < 3; ++ky)
#pragma unroll
            for (int kx = 0; kx < 3; ++kx)
                acc = fmaf(bf2f(t1[((yy+ky)*10 + xx+kx)*64 + c]),
                           w2r[ky*3+kx], acc);
        out[(((size_t)b*256 + y0+yy)*256 + x0+xx)*64 + c] += acc;
    }
}

extern "C" void kernel_launch(void* const* d_in, const int* in_sizes, int n_in,
                              void* d_out, int out_size, void* d_ws, size_t ws_size,
                              hipStream_t stream)
{
    const float* x    = (const float*)d_in[0];
    const float* mask = (const float*)d_in[1];
    const float* Wq   = (const float*)d_in[2];
    const float* Wk   = (const float*)d_in[3];
    const float* Wv   = (const float*)d_in[4];
    const float* resc = (const float*)d_in[5];
    const float* Wp   = (const float*)d_in[6];
    const float* bp   = (const float*)d_in[7];
    const float* mw1  = (const float*)d_in[8];
    const float* mb1  = (const float*)d_in[9];
    const float* mw2  = (const float*)d_in[10];
    const float* mb2  = (const float*)d_in[11];
    const float* mdw  = (const float*)d_in[12];
    const float* mdwb = (const float*)d_in[13];
    const float* pw1  = (const float*)d_in[14];
    const float* pw2  = (const float*)d_in[15];
    float* ws  = (float*)d_ws;
    unsigned short* wg = (unsigned short*)((char*)d_ws + WS_WSWZ_BYTE);
    __hip_bfloat16* m2 = (__hip_bfloat16*)((char*)d_ws + WS_M2_BYTE);
    float* out = (float*)d_out;

    hipMemsetAsync(ws, 0, (size_t)9216*sizeof(float), stream);   // G + ssq slots

    k_prep <<<80,   256, 0, stream>>>(Wq, Wk, Wv, mw1, mw2, wg);
    k_fused<<<1024, 256, 0, stream>>>(x, mask, wg, mb1, mb2, ws, out, m2);
    k_attn <<<2,    256, 0, stream>>>(resc, Wp, ws);
    k_final<<<2048, 256, 0, stream>>>(m2, ws + WS_M, bp, mdw, mdwb, out);
    k_pe   <<<2048, 256, 0, stream>>>(x, pw1, pw2, out);
}

// Round 2
// 325.786 us; speedup vs baseline: 1.2966x; 1.2966x over previous
//
#include <hip/hip_runtime.h>
#include <hip/hip_bf16.h>
#include <math.h>

#define BB 2
#define NPIX 131072            // 2*256*256

// ws float header (4-slot accumulators)
#define WS_G    0              // [slot4][B][1024]  (G[c=h*16+d][e])
#define WS_SSQ  8192           // [slot4][2][B][64] (0=q,1=k)
#define WS_M    9216           // [B][4096] folded Wp*blockdiag(attn), transposed
#define WS_WSWZ_BYTE ((size_t)17408*4)            // 20480 ushort pre-swizzled weights (40 KB)
#define WS_M2_BYTE   (WS_WSWZ_BYTE + 40960)       // m2 bf16: NPIX*64*2 = 16.78 MB

typedef __attribute__((ext_vector_type(8))) short short8;
typedef __attribute__((ext_vector_type(4))) float f32x4;

__device__ __forceinline__ unsigned short f2bf(float f) {
    unsigned u = __float_as_uint(f);
    u += 0x7FFFu + ((u >> 16) & 1u);            // RNE
    return (unsigned short)(u >> 16);
}
__device__ __forceinline__ float bf2f(unsigned short s) {
    return __uint_as_float((unsigned)s << 16);
}
__device__ __forceinline__ void lds_fence() {
    __asm__ __volatile__("s_waitcnt lgkmcnt(0)" ::: "memory");
}

// ---------------------------------------------------------------------------
// K0: pre-swizzle the 5 weight matrices into MFMA B-frag order, bf16, in ws.
// frag f = matot*2+kh; element (f, lane l, j) = W[ot*16+(l&15)][kh*32+((l>>4)&3)*8+j]
// ---------------------------------------------------------------------------
__global__ __launch_bounds__(256) void k_prep(const float* __restrict__ Wq,
    const float* __restrict__ Wk, const float* __restrict__ Wv,
    const float* __restrict__ w1, const float* __restrict__ w2,
    unsigned short* __restrict__ wg)
{
    const int i = blockIdx.x*256 + threadIdx.x;     // 80 blocks -> 20480
    const int f = i >> 9, l = (i >> 3) & 63, j = i & 7;
    const int matot = f >> 1, kh = f & 1;
    const int mat = matot >> 2, ot = matot & 3;
    const int o = ot*16 + (l & 15);
    const int cc = kh*32 + ((l >> 4) & 3)*8 + j;
    const float* Wsrc[5] = {Wq, Wk, Wv, w1, w2};
    wg[i] = f2bf(Wsrc[mat][o*64 + cc]);
}

// ---------------------------------------------------------------------------
// K1 (MFMA, fused): 512 blocks x 512 threads (8 waves), 256 px/block:
//   q,k,v = x@{Wq,Wk,Wv}^T ; m1 = mask@w1^T+b1 ; vm0 = v*m1 -> d_out (fp32);
//   m2 = m1@w2^T+b2 -> ws bf16 ; Gram G + ssq -> 4-slot atomics.
// Weights in LDS (40 KB, shared by 8 waves; loads stay short-latency LDS,
// no L1-miss chain, no VGPR pressure). LDS = 40 + 34 + 4 = 78 KB ->
// 2 blocks/CU = 16 waves/CU = 4 waves/SIMD (round-0 had only 2/SIMD).
// __launch_bounds__(512,4): exactly 2 blocks/CU, VGPR cap 128 (body needs
// ~100 -> NO spill; round-1's (256,4)+global-weights spilled at VGPR=64).
// ---------------------------------------------------------------------------
__global__ __launch_bounds__(512, 4) void k_fused(
    const float* __restrict__ x, const float* __restrict__ mask,
    const unsigned short* __restrict__ wg,
    const float* __restrict__ b1, const float* __restrict__ b2,
    float* __restrict__ ws, float* __restrict__ out,
    __hip_bfloat16* __restrict__ m2out)
{
    __shared__ unsigned short wswz[20480];          // 40 KB
    __shared__ unsigned short scr[8][2176];         // 4.25 KB per wave (34 KB)
    __shared__ float s_ssq[8][2][64];               // 4 KB
    const int tid = threadIdx.x, lane = tid & 63, w = tid >> 6;
    const int quad = lane >> 4, col = lane & 15;
    const int blk = blockIdx.x, b = blk >> 8, slot = blk & 3;

    for (int i = tid; i < 2560; i += 512)           // 40KB contiguous b128
        ((uint4*)wswz)[i] = ((const uint4*)wg)[i];
    __syncthreads();

    float b1v[4], b2v[4];
#pragma unroll
    for (int ot = 0; ot < 4; ++ot) {
        b1v[ot] = b1[ot*16 + col];
        b2v[ot] = b2[ot*16 + col];
    }

#define WFRAG(matot, kh) (*(const short8*)&wswz[(((matot)*2 + (kh))*64 + lane)*8])

    float accG[16];
#pragma unroll
    for (int e = 0; e < 16; ++e) accG[e] = 0.f;
    float ssq_q = 0.f, ssq_k = 0.f;
    const int hbase = lane & 48;
    unsigned short* S = scr[w];

    for (int t = 0; t < 2; ++t) {
        const int pbase = blk*256 + t*128 + w*16;

        // A-frags from global (fp32 -> bf16): A[m=col(px)][k=quad*8+j (+32kh)]
        short8 xA[2], mA[2];
        {
            const float* xs = x    + ((size_t)(pbase + col))*64 + quad*8;
            const float* ms = mask + ((size_t)(pbase + col))*64 + quad*8;
#pragma unroll
            for (int kh = 0; kh < 2; ++kh) {
                float4 a0 = *(const float4*)(xs + kh*32);
                float4 a1 = *(const float4*)(xs + kh*32 + 4);
                float4 b0 = *(const float4*)(ms + kh*32);
                float4 b1f = *(const float4*)(ms + kh*32 + 4);
#pragma unroll
                for (int j = 0; j < 4; ++j) {
                    xA[kh][j]   = (short)f2bf((&a0.x)[j]);
                    xA[kh][4+j] = (short)f2bf((&a1.x)[j]);
                    mA[kh][j]   = (short)f2bf((&b0.x)[j]);
                    mA[kh][4+j] = (short)f2bf((&b1f.x)[j]);
                }
            }
        }

        // Phase A: q,k -> S as ushort [mat][p][68]
#pragma unroll
        for (int mm = 0; mm < 2; ++mm) {
#pragma unroll
            for (int ot = 0; ot < 4; ++ot) {
                f32x4 a = {0.f, 0.f, 0.f, 0.f};
                a = __builtin_amdgcn_mfma_f32_16x16x32_bf16(xA[0], WFRAG(mm*4+ot,0), a, 0,0,0);
                a = __builtin_amdgcn_mfma_f32_16x16x32_bf16(xA[1], WFRAG(mm*4+ot,1), a, 0,0,0);
#pragma unroll
                for (int r = 0; r < 4; ++r)
                    S[mm*1088 + (quad*4+r)*68 + ot*16 + col] = f2bf(a[r]);
            }
        }
        __builtin_amdgcn_wave_barrier();
        // Gram + ssq (lane = channel c): G[c][e] += k[p][c]*q[p][(c&48)+e]
#pragma unroll
        for (int p = 0; p < 16; ++p) {
            const float kv = bf2f(S[1088 + p*68 + lane]);
            const float qo = bf2f(S[p*68 + lane]);
            ssq_k = fmaf(kv, kv, ssq_k);
            ssq_q = fmaf(qo, qo, ssq_q);
#pragma unroll
            for (int e4 = 0; e4 < 4; ++e4) {
                ushort4 qq = *(const ushort4*)&S[p*68 + hbase + e4*4];
                accG[e4*4+0] = fmaf(kv, bf2f(qq.x), accG[e4*4+0]);
                accG[e4*4+1] = fmaf(kv, bf2f(qq.y), accG[e4*4+1]);
                accG[e4*4+2] = fmaf(kv, bf2f(qq.z), accG[e4*4+2]);
                accG[e4*4+3] = fmaf(kv, bf2f(qq.w), accG[e4*4+3]);
            }
        }
        lds_fence();                    // Gram reads done before S reused

        // v, m1
        f32x4 vfr[4], m1fr[4];
#pragma unroll
        for (int ot = 0; ot < 4; ++ot) {
            f32x4 a = {0.f, 0.f, 0.f, 0.f};
            a = __builtin_amdgcn_mfma_f32_16x16x32_bf16(xA[0], WFRAG(8+ot,0), a, 0,0,0);
            a = __builtin_amdgcn_mfma_f32_16x16x32_bf16(xA[1], WFRAG(8+ot,1), a, 0,0,0);
            vfr[ot] = a;
        }
#pragma unroll
        for (int ot = 0; ot < 4; ++ot) {
            f32x4 a = {0.f, 0.f, 0.f, 0.f};
            a = __builtin_amdgcn_mfma_f32_16x16x32_bf16(mA[0], WFRAG(12+ot,0), a, 0,0,0);
            a = __builtin_amdgcn_mfma_f32_16x16x32_bf16(mA[1], WFRAG(12+ot,1), a, 0,0,0);
#pragma unroll
            for (int r = 0; r < 4; ++r) a[r] += b1v[ot];
            m1fr[ot] = a;
        }

        // Phase B: vm0 fp32 [16][66] in S, then coalesced 512B row stores
        float* vscr = (float*)S;
#pragma unroll
        for (int ot = 0; ot < 4; ++ot)
#pragma unroll
            for (int r = 0; r < 4; ++r)
                vscr[(quad*4+r)*66 + ot*16 + col] = vfr[ot][r] * m1fr[ot][r];
        __builtin_amdgcn_wave_barrier();
        {
            const int rb = lane >> 5, ci = (lane & 31)*2;
#pragma unroll
            for (int pp = 0; pp < 8; ++pp) {
                const int row = pp*2 + rb;
                float2 v2 = *(const float2*)&vscr[row*66 + ci];
                *(float2*)&out[((size_t)(pbase + row))*64 + ci] = v2;
            }
        }
        lds_fence();                    // vm0 reads done before S reused

        // Phase C: m1 bf16 [16][72] in S -> A-frags for m2
#pragma unroll
        for (int ot = 0; ot < 4; ++ot)
#pragma unroll
            for (int r = 0; r < 4; ++r)
                S[(quad*4+r)*72 + ot*16 + col] = f2bf(m1fr[ot][r]);
        __builtin_amdgcn_wave_barrier();
        short8 a2[2];
#pragma unroll
        for (int kh = 0; kh < 2; ++kh)
            a2[kh] = *(const short8*)&S[col*72 + kh*32 + quad*8];
        lds_fence();                    // a2 reads done before S overwritten

        // Phase D: m2 mfma, bf16 [16][72] in S, coalesced packed-uint stores
#pragma unroll
        for (int ot = 0; ot < 4; ++ot) {
            f32x4 a = {0.f, 0.f, 0.f, 0.f};
            a = __builtin_amdgcn_mfma_f32_16x16x32_bf16(a2[0], WFRAG(16+ot,0), a, 0,0,0);
            a = __builtin_amdgcn_mfma_f32_16x16x32_bf16(a2[1], WFRAG(16+ot,1), a, 0,0,0);
#pragma unroll
            for (int r = 0; r < 4; ++r)
                S[(quad*4+r)*72 + ot*16 + col] = f2bf(a[r] + b2v[ot]);
        }
        __builtin_amdgcn_wave_barrier();
        {
            unsigned short* m2u = (unsigned short*)m2out;
            const int rb = lane >> 5, ci = (lane & 31)*2;
#pragma unroll
            for (int pp = 0; pp < 8; ++pp) {
                const int row = pp*2 + rb;
                unsigned vv = *(const unsigned*)&S[row*72 + ci];
                *(unsigned*)&m2u[((size_t)(pbase + row))*64 + ci] = vv;
            }
        }
        lds_fence();                    // m2 reads done before next iter
    }

    __syncthreads();                    // all waves done with scr

    // block reduction of G: each wave writes its [16][64] slab (8192 floats
    // = 32 KB, fits the 34 KB scr), then 512 threads sum 8 slabs -> atomics.
    float* gr = (float*)&scr[0][0];
#pragma unroll
    for (int e = 0; e < 16; ++e) gr[w*1024 + e*64 + lane] = accG[e];
    s_ssq[w][0][lane] = ssq_q;
    s_ssq[w][1][lane] = ssq_k;
    __syncthreads();
    float* Gg = ws + WS_G + (size_t)slot*2048 + (size_t)b*1024;
    for (int idx = tid; idx < 1024; idx += 512) {
        const int e = idx >> 6, c = idx & 63;
        float s = 0.f;
#pragma unroll
        for (int wv = 0; wv < 8; ++wv) s += gr[wv*1024 + idx];
        atomicAdd(&Gg[c*16 + e], s);
    }
    if (tid < 128) {
        const int which = tid >> 6, cidx = tid & 63;
        float s = 0.f;
#pragma unroll
        for (int wv = 0; wv < 8; ++wv) s += s_ssq[wv][which][cidx];
        atomicAdd(ws + WS_SSQ + (size_t)slot*256 + which*128 + b*64 + cidx, s);
    }
#undef WFRAG
}

// ---------------------------------------------------------------------------
// K2: softmax over normalized Gram (sum 4 slots), folded with Wp:
//   Mt[b][c=h*16+e][o] = sum_d Wp[o][h*16+d] * attn[b][h][d][e].  2 blocks.
// ---------------------------------------------------------------------------
__global__ __launch_bounds__(256) void k_attn(const float* __restrict__ rescale,
    const float* __restrict__ Wp, float* __restrict__ ws)
{
    __shared__ float sAtt[1024];        // [h][d][e]
    const int b = blockIdx.x, t = threadIdx.x;
    const int d = t >> 4, e = t & 15;
#pragma unroll
    for (int h = 0; h < 4; ++h) {
        float g = 0.f, nk2 = 0.f, nq2 = 0.f;
#pragma unroll
        for (int s = 0; s < 4; ++s) {
            g   += ws[WS_G + s*2048 + b*1024 + (h*16+d)*16 + e];
            nk2 += ws[WS_SSQ + s*256 + 128 + b*64 + h*16 + d];
            nq2 += ws[WS_SSQ + s*256 +   0 + b*64 + h*16 + e];
        }
        float nk = fmaxf(sqrtf(nk2), 1e-12f);
        float nq = fmaxf(sqrtf(nq2), 1e-12f);
        float val = g / (nk*nq) * rescale[h];
        float m = val;
        for (int off = 1; off < 16; off <<= 1) m = fmaxf(m, __shfl_xor(m, off, 16));
        float ev = expf(val - m);
        float s2 = ev;
        for (int off = 1; off < 16; off <<= 1) s2 += __shfl_xor(s2, off, 16);
        sAtt[h*256 + d*16 + e] = ev / s2;
    }
    __syncthreads();
    float* Mtb = ws + WS_M + (size_t)b*4096;
    for (int idx = t; idx < 4096; idx += 256) {
        const int c = idx >> 6, o = idx & 63, h = c >> 4, ee = c & 15;
        float acc = 0.f;
#pragma unroll
        for (int d2 = 0; d2 < 16; ++d2)
            acc = fmaf(Wp[o*64 + h*16 + d2], sAtt[h*256 + d2*16 + ee], acc);
        Mtb[c*64 + o] = acc;
    }
}

// ---------------------------------------------------------------------------
// K3: per 8x8 tile: dwconv5x5(m2 bf16 halo)+dwb -> sigmoid ->
//   vm = vm0(d_out)*(1+sig) -> out = Mt . vm + bp.
// ---------------------------------------------------------------------------
__global__ __launch_bounds__(256, 4) void k_final(
    const __hip_bfloat16* __restrict__ m2g, const float* __restrict__ wsM,
    const float* __restrict__ bp, const float* __restrict__ dw,
    const float* __restrict__ dwb, float* __restrict__ out)
{
    __shared__ unsigned short m2s[144*64];  // 18.4 KB bf16 halo (0 outside)
    __shared__ unsigned short Mtl[4096];    // 8 KB bf16 blocked-f4 [c4][o][u]
    __shared__ float s_vm[4][4][64];        // per-wave
    const int tid = threadIdx.x, lane = tid & 63, w = tid >> 6;
    const int bid = blockIdx.x;
    const int b = bid >> 10, tile = bid & 1023;
    const int y0 = (tile >> 5) * 8, x0 = (tile & 31) * 8;
    const int c = lane;

    const float* Msrc = wsM + (size_t)b*4096;
    for (int i = tid; i < 4096; i += 256) {
        const int o = (i >> 2) & 63, gc = (i >> 8) * 4 + (i & 3);
        Mtl[i] = f2bf(Msrc[gc*64 + o]);
    }
    for (int i2 = tid; i2 < 2304; i2 += 256) {
        const int pos = i2 >> 4, c4 = (i2 & 15) * 4;
        const int yy = pos / 12, xx = pos - yy*12;
        const int gy = y0 + yy - 2, gx = x0 + xx - 2;
        ushort4 us = make_ushort4(0, 0, 0, 0);
        if (gy >= 0 && gy < 256 && gx >= 0 && gx < 256)
            us = *(const ushort4*)&m2g[(((size_t)b*256 + gy)*256 + gx)*64 + c4];
        *(ushort4*)&m2s[pos*64 + c4] = us;
    }
    __syncthreads();

    const float dwbr = dwb[c], bpr = bp[c];
    float dwr[25];
#pragma unroll
    for (int k = 0; k < 25; ++k) dwr[k] = dw[c*25+k];

    for (int g = 0; g < 4; ++g) {
        const int p0 = w*16 + g*4;          // 4 consecutive px in one row
        const int py = p0 >> 3, px0 = p0 & 7;
        float acc[4] = {dwbr, dwbr, dwbr, dwbr};
#pragma unroll
        for (int ky = 0; ky < 5; ++ky) {
            const int rbase = ((py+ky)*12 + px0)*64 + c;
#pragma unroll
            for (int kx8 = 0; kx8 < 8; ++kx8) {
                const float tv = bf2f(m2s[rbase + kx8*64]);
#pragma unroll
                for (int j = 0; j < 4; ++j) {
                    const int kk = kx8 - j;
                    if (kk >= 0 && kk < 5)
                        acc[j] = fmaf(tv, dwr[ky*5 + kk], acc[j]);
                }
            }
        }
        size_t P[4];
#pragma unroll
        for (int j = 0; j < 4; ++j) {
            P[j] = (size_t)b*65536 + (size_t)(y0+py)*256 + (x0+px0+j);
            const float s = 1.f / (1.f + expf(-acc[j]));
            s_vm[w][j][c] = out[P[j]*64 + c] * (1.f + s);   // vm0 * (1+sig)
        }
        __builtin_amdgcn_wave_barrier();
        float oc[4] = {bpr, bpr, bpr, bpr};
        for (int c4 = 0; c4 < 16; ++c4) {
            float4 v4[4];
#pragma unroll
            for (int j = 0; j < 4; ++j)
                v4[j] = *(const float4*)&s_vm[w][j][c4*4];  // broadcast
            const ushort4 m4 = *(const ushort4*)&Mtl[c4*256 + lane*4];
            const float mf[4] = {bf2f(m4.x), bf2f(m4.y), bf2f(m4.z), bf2f(m4.w)};
#pragma unroll
            for (int u = 0; u < 4; ++u)
#pragma unroll
                for (int j = 0; j < 4; ++j)
                    oc[j] = fmaf((&v4[j].x)[u], mf[u], oc[j]);
        }
#pragma unroll
        for (int j = 0; j < 4; ++j)
            out[P[j]*64 + c] = oc[j];
        __builtin_amdgcn_wave_barrier();
    }
}

// ---------------------------------------------------------------------------
// K4 (last): PE branch dwconv3x3 -> gelu -> dwconv3x3, += d_out.
// xt and t1 bf16 in LDS; t1 outside image is ZERO (conv2 padding).
// ---------------------------------------------------------------------------
__global__ __launch_bounds__(256, 5) void k_pe(const float* __restrict__ x,
    const float* __restrict__ w1, const float* __restrict__ w2,
    float* __restrict__ out)
{
    __shared__ unsigned short xt[12*12*64];     // 18.4 KB bf16
    __shared__ unsigned short t1[10*10*64];     // 12.8 KB bf16
    const int tid = threadIdx.x;
    const int bid = blockIdx.x;
    const int b = bid >> 10, tile = bid & 1023;
    const int y0 = (tile >> 5) * 8, x0 = (tile & 31) * 8;
    const int c = tid & 63;
    float w1r[9], w2r[9];
#pragma unroll
    for (int k = 0; k < 9; ++k) { w1r[k] = w1[c*9+k]; w2r[k] = w2[c*9+k]; }

    for (int i = tid; i < 12*12*64; i += 256) {
        int yy = i / 768, xx = (i % 768) >> 6;
        int gy = y0 + yy - 2, gx = x0 + xx - 2;
        float v = 0.f;
        if (gy >= 0 && gy < 256 && gx >= 0 && gx < 256)
            v = x[(((size_t)b*256 + gy)*256 + gx)*64 + c];
        xt[i] = f2bf(v);
    }
    __syncthreads();
    for (int i = tid; i < 10*10*64; i += 256) {
        int yy = i / 640, xx = (i % 640) >> 6;
        int gy = y0 + yy - 1, gx = x0 + xx - 1;
        float val = 0.f;
        if (gy >= 0 && gy < 256 && gx >= 0 && gx < 256) {
            float acc = 0.f;
#pragma unroll
            for (int ky = 0; ky < 3; ++ky)
#pragma unroll
                for (int kx = 0; kx < 3; ++kx)
                    acc = fmaf(bf2f(xt[((yy+ky)*12 + xx+kx)*64 + c]),
                               w1r[ky*3+kx], acc);
            val = 0.5f * acc * (1.f + erff(acc * 0.70710678118654752f));
        }
        t1[i] = f2bf(val);
    }
    __syncthreads();
    for (int i = tid; i < 8*8*64; i += 256) {
        int yy = i / 512, xx = (i % 512) >> 6;
        float acc = 0.f;
#pragma unroll
        for (int ky = 0; ky < 3; ++ky)
#pragma unroll
            for (int kx = 0; kx < 3; ++kx)
                acc = fmaf(bf2f(t1[((yy+ky)*10 + xx+kx)*64 + c]),
                           w2r[ky*3+kx], acc);
        out[(((size_t)b*256 + y0+yy)*256 + x0+xx)*64 + c] += acc;
    }
}

extern "C" void kernel_launch(void* const* d_in, const int* in_sizes, int n_in,
                              void* d_out, int out_size, void* d_ws, size_t ws_size,
                              hipStream_t stream)
{
    const float* x    = (const float*)d_in[0];
    const float* mask = (const float*)d_in[1];
    const float* Wq   = (const float*)d_in[2];
    const float* Wk   = (const float*)d_in[3];
    const float* Wv   = (const float*)d_in[4];
    const float* resc = (const float*)d_in[5];
    const float* Wp   = (const float*)d_in[6];
    const float* bp   = (const float*)d_in[7];
    const float* mw1  = (const float*)d_in[8];
    const float* mb1  = (const float*)d_in[9];
    const float* mw2  = (const float*)d_in[10];
    const float* mb2  = (const float*)d_in[11];
    const float* mdw  = (const float*)d_in[12];
    const float* mdwb = (const float*)d_in[13];
    const float* pw1  = (const float*)d_in[14];
    const float* pw2  = (const float*)d_in[15];
    float* ws  = (float*)d_ws;
    unsigned short* wg = (unsigned short*)((char*)d_ws + WS_WSWZ_BYTE);
    __hip_bfloat16* m2 = (__hip_bfloat16*)((char*)d_ws + WS_M2_BYTE);
    float* out = (float*)d_out;

    hipMemsetAsync(ws, 0, (size_t)9216*sizeof(float), stream);   // G + ssq slots

    k_prep <<<80,   256, 0, stream>>>(Wq, Wk, Wv, mw1, mw2, wg);
    k_fused<<<512,  512, 0, stream>>>(x, mask, wg, mb1, mb2, ws, out, m2);
    k_attn <<<2,    256, 0, stream>>>(resc, Wp, ws);
    k_final<<<2048, 256, 0, stream>>>(m2, ws + WS_M, bp, mdw, mdwb, out);
    k_pe   <<<2048, 256, 0, stream>>>(x, pw1, pw2, out);
}

// Round 5
// 303.225 us; speedup vs baseline: 1.3931x; 1.0744x over previous
//
#include <hip/hip_runtime.h>
#include <hip/hip_bf16.h>
#include <math.h>

#define BB 2
#define NPIX 131072            // 2*256*256

// ws float header (4-slot accumulators)
#define WS_G    0              // [slot4][B][1024]  (G[c=h*16+d][e])
#define WS_SSQ  8192           // [slot4][2][B][64] (0=q,1=k)
#define WS_M    9216           // [B][4096] folded Wp*blockdiag(attn), transposed
#define WS_WSWZ_BYTE ((size_t)17408*4)            // 20480 ushort pre-swizzled weights (40 KB)
#define WS_M2_BYTE   (WS_WSWZ_BYTE + 40960)       // m2 bf16: NPIX*64*2 = 16.78 MB

typedef __attribute__((ext_vector_type(8))) short short8;
typedef __attribute__((ext_vector_type(4))) float f32x4;

__device__ __forceinline__ unsigned short f2bf(float f) {
    unsigned u = __float_as_uint(f);
    u += 0x7FFFu + ((u >> 16) & 1u);            // RNE
    return (unsigned short)(u >> 16);
}
__device__ __forceinline__ float bf2f(unsigned short s) {
    return __uint_as_float((unsigned)s << 16);
}
__device__ __forceinline__ void lds_fence() {
    __asm__ __volatile__("s_waitcnt lgkmcnt(0)" ::: "memory");
}

// ---------------------------------------------------------------------------
// K0: pre-swizzle the 5 weight matrices into MFMA B-frag order, bf16, in ws.
// frag f = matot*2+kh; element (f, lane l, j) = W[ot*16+(l&15)][kh*32+((l>>4)&3)*8+j]
// ---------------------------------------------------------------------------
__global__ __launch_bounds__(256) void k_prep(const float* __restrict__ Wq,
    const float* __restrict__ Wk, const float* __restrict__ Wv,
    const float* __restrict__ w1, const float* __restrict__ w2,
    unsigned short* __restrict__ wg)
{
    const int i = blockIdx.x*256 + threadIdx.x;     // 80 blocks -> 20480
    const int f = i >> 9, l = (i >> 3) & 63, j = i & 7;
    const int matot = f >> 1, kh = f & 1;
    const int mat = matot >> 2, ot = matot & 3;
    const int o = ot*16 + (l & 15);
    const int cc = kh*32 + ((l >> 4) & 3)*8 + j;
    const float* Wsrc[5] = {Wq, Wk, Wv, w1, w2};
    wg[i] = f2bf(Wsrc[mat][o*64 + cc]);
}

// ---------------------------------------------------------------------------
// K1 (MFMA, fused): 512 blocks x 512 threads (8 waves), 256 px/block:
//   q,k,v = x@{Wq,Wk,Wv}^T ; m1 = mask@w1^T+b1 ; vm0 = v*m1 -> d_out (fp32);
//   m2 = m1@w2^T+b2 -> ws bf16 ; Gram G + ssq -> 4-slot atomics.
// Weights in LDS (40 KB, shared by 8 waves). LDS = 40 + 34 + 4 = 78 KB ->
// 2 blocks/CU = 16 waves/CU = 4 waves/SIMD.
// LAUNCH BOUNDS: empirically cap = 256/min_waves_arg: arg=4 -> 64-VGPR cap
// -> spills (r1: FETCH 204MB, r2: 92MB vs 33MB clean). arg=2 -> 128 cap;
// body needs ~100 (r0 evidence) -> NO spill, and LDS still gives 2 blk/CU.
// ---------------------------------------------------------------------------
__global__ __launch_bounds__(512, 2) void k_fused(
    const float* __restrict__ x, const float* __restrict__ mask,
    const unsigned short* __restrict__ wg,
    const float* __restrict__ b1, const float* __restrict__ b2,
    float* __restrict__ ws, float* __restrict__ out,
    __hip_bfloat16* __restrict__ m2out)
{
    __shared__ unsigned short wswz[20480];          // 40 KB
    __shared__ unsigned short scr[8][2176];         // 4.25 KB per wave (34 KB)
    __shared__ float s_ssq[8][2][64];               // 4 KB
    const int tid = threadIdx.x, lane = tid & 63, w = tid >> 6;
    const int quad = lane >> 4, col = lane & 15;
    const int blk = blockIdx.x, b = blk >> 8, slot = blk & 3;

    for (int i = tid; i < 2560; i += 512)           // 40KB contiguous b128
        ((uint4*)wswz)[i] = ((const uint4*)wg)[i];
    __syncthreads();

    float b1v[4], b2v[4];
#pragma unroll
    for (int ot = 0; ot < 4; ++ot) {
        b1v[ot] = b1[ot*16 + col];
        b2v[ot] = b2[ot*16 + col];
    }

#define WFRAG(matot, kh) (*(const short8*)&wswz[(((matot)*2 + (kh))*64 + lane)*8])

    float accG[16];
#pragma unroll
    for (int e = 0; e < 16; ++e) accG[e] = 0.f;
    float ssq_q = 0.f, ssq_k = 0.f;
    const int hbase = lane & 48;
    unsigned short* S = scr[w];

    for (int t = 0; t < 2; ++t) {
        const int pbase = blk*256 + t*128 + w*16;

        // A-frags from global (fp32 -> bf16): A[m=col(px)][k=quad*8+j (+32kh)]
        short8 xA[2], mA[2];
        {
            const float* xs = x    + ((size_t)(pbase + col))*64 + quad*8;
            const float* ms = mask + ((size_t)(pbase + col))*64 + quad*8;
#pragma unroll
            for (int kh = 0; kh < 2; ++kh) {
                float4 a0 = *(const float4*)(xs + kh*32);
                float4 a1 = *(const float4*)(xs + kh*32 + 4);
                float4 b0 = *(const float4*)(ms + kh*32);
                float4 b1f = *(const float4*)(ms + kh*32 + 4);
#pragma unroll
                for (int j = 0; j < 4; ++j) {
                    xA[kh][j]   = (short)f2bf((&a0.x)[j]);
                    xA[kh][4+j] = (short)f2bf((&a1.x)[j]);
                    mA[kh][j]   = (short)f2bf((&b0.x)[j]);
                    mA[kh][4+j] = (short)f2bf((&b1f.x)[j]);
                }
            }
        }

        // Phase A: q,k -> S as ushort [mat][p][68]
#pragma unroll
        for (int mm = 0; mm < 2; ++mm) {
#pragma unroll
            for (int ot = 0; ot < 4; ++ot) {
                f32x4 a = {0.f, 0.f, 0.f, 0.f};
                a = __builtin_amdgcn_mfma_f32_16x16x32_bf16(xA[0], WFRAG(mm*4+ot,0), a, 0,0,0);
                a = __builtin_amdgcn_mfma_f32_16x16x32_bf16(xA[1], WFRAG(mm*4+ot,1), a, 0,0,0);
#pragma unroll
                for (int r = 0; r < 4; ++r)
                    S[mm*1088 + (quad*4+r)*68 + ot*16 + col] = f2bf(a[r]);
            }
        }
        __builtin_amdgcn_wave_barrier();
        // Gram + ssq (lane = channel c): G[c][e] += k[p][c]*q[p][(c&48)+e]
#pragma unroll
        for (int p = 0; p < 16; ++p) {
            const float kv = bf2f(S[1088 + p*68 + lane]);
            const float qo = bf2f(S[p*68 + lane]);
            ssq_k = fmaf(kv, kv, ssq_k);
            ssq_q = fmaf(qo, qo, ssq_q);
#pragma unroll
            for (int e4 = 0; e4 < 4; ++e4) {
                ushort4 qq = *(const ushort4*)&S[p*68 + hbase + e4*4];
                accG[e4*4+0] = fmaf(kv, bf2f(qq.x), accG[e4*4+0]);
                accG[e4*4+1] = fmaf(kv, bf2f(qq.y), accG[e4*4+1]);
                accG[e4*4+2] = fmaf(kv, bf2f(qq.z), accG[e4*4+2]);
                accG[e4*4+3] = fmaf(kv, bf2f(qq.w), accG[e4*4+3]);
            }
        }
        lds_fence();                    // Gram reads done before S reused

        // v, m1
        f32x4 vfr[4], m1fr[4];
#pragma unroll
        for (int ot = 0; ot < 4; ++ot) {
            f32x4 a = {0.f, 0.f, 0.f, 0.f};
            a = __builtin_amdgcn_mfma_f32_16x16x32_bf16(xA[0], WFRAG(8+ot,0), a, 0,0,0);
            a = __builtin_amdgcn_mfma_f32_16x16x32_bf16(xA[1], WFRAG(8+ot,1), a, 0,0,0);
            vfr[ot] = a;
        }
#pragma unroll
        for (int ot = 0; ot < 4; ++ot) {
            f32x4 a = {0.f, 0.f, 0.f, 0.f};
            a = __builtin_amdgcn_mfma_f32_16x16x32_bf16(mA[0], WFRAG(12+ot,0), a, 0,0,0);
            a = __builtin_amdgcn_mfma_f32_16x16x32_bf16(mA[1], WFRAG(12+ot,1), a, 0,0,0);
#pragma unroll
            for (int r = 0; r < 4; ++r) a[r] += b1v[ot];
            m1fr[ot] = a;
        }

        // Phase B: vm0 fp32 [16][66] in S, then coalesced 512B row stores
        float* vscr = (float*)S;
#pragma unroll
        for (int ot = 0; ot < 4; ++ot)
#pragma unroll
            for (int r = 0; r < 4; ++r)
                vscr[(quad*4+r)*66 + ot*16 + col] = vfr[ot][r] * m1fr[ot][r];
        __builtin_amdgcn_wave_barrier();
        {
            const int rb = lane >> 5, ci = (lane & 31)*2;
#pragma unroll
            for (int pp = 0; pp < 8; ++pp) {
                const int row = pp*2 + rb;
                float2 v2 = *(const float2*)&vscr[row*66 + ci];
                *(float2*)&out[((size_t)(pbase + row))*64 + ci] = v2;
            }
        }
        lds_fence();                    // vm0 reads done before S reused

        // Phase C: m1 bf16 [16][72] in S -> A-frags for m2
#pragma unroll
        for (int ot = 0; ot < 4; ++ot)
#pragma unroll
            for (int r = 0; r < 4; ++r)
                S[(quad*4+r)*72 + ot*16 + col] = f2bf(m1fr[ot][r]);
        __builtin_amdgcn_wave_barrier();
        short8 a2[2];
#pragma unroll
        for (int kh = 0; kh < 2; ++kh)
            a2[kh] = *(const short8*)&S[col*72 + kh*32 + quad*8];
        lds_fence();                    // a2 reads done before S overwritten

        // Phase D: m2 mfma, bf16 [16][72] in S, coalesced packed-uint stores
#pragma unroll
        for (int ot = 0; ot < 4; ++ot) {
            f32x4 a = {0.f, 0.f, 0.f, 0.f};
            a = __builtin_amdgcn_mfma_f32_16x16x32_bf16(a2[0], WFRAG(16+ot,0), a, 0,0,0);
            a = __builtin_amdgcn_mfma_f32_16x16x32_bf16(a2[1], WFRAG(16+ot,1), a, 0,0,0);
#pragma unroll
            for (int r = 0; r < 4; ++r)
                S[(quad*4+r)*72 + ot*16 + col] = f2bf(a[r] + b2v[ot]);
        }
        __builtin_amdgcn_wave_barrier();
        {
            unsigned short* m2u = (unsigned short*)m2out;
            const int rb = lane >> 5, ci = (lane & 31)*2;
#pragma unroll
            for (int pp = 0; pp < 8; ++pp) {
                const int row = pp*2 + rb;
                unsigned vv = *(const unsigned*)&S[row*72 + ci];
                *(unsigned*)&m2u[((size_t)(pbase + row))*64 + ci] = vv;
            }
        }
        lds_fence();                    // m2 reads done before next iter
    }

    __syncthreads();                    // all waves done with scr

    // block reduction of G: each wave writes its [16][64] slab (8192 floats
    // = 32 KB, fits the 34 KB scr), then 512 threads sum 8 slabs -> atomics.
    float* gr = (float*)&scr[0][0];
#pragma unroll
    for (int e = 0; e < 16; ++e) gr[w*1024 + e*64 + lane] = accG[e];
    s_ssq[w][0][lane] = ssq_q;
    s_ssq[w][1][lane] = ssq_k;
    __syncthreads();
    float* Gg = ws + WS_G + (size_t)slot*2048 + (size_t)b*1024;
    for (int idx = tid; idx < 1024; idx += 512) {
        const int e = idx >> 6, c = idx & 63;
        float s = 0.f;
#pragma unroll
        for (int wv = 0; wv < 8; ++wv) s += gr[wv*1024 + idx];
        atomicAdd(&Gg[c*16 + e], s);
    }
    if (tid < 128) {
        const int which = tid >> 6, cidx = tid & 63;
        float s = 0.f;
#pragma unroll
        for (int wv = 0; wv < 8; ++wv) s += s_ssq[wv][which][cidx];
        atomicAdd(ws + WS_SSQ + (size_t)slot*256 + which*128 + b*64 + cidx, s);
    }
#undef WFRAG
}

// ---------------------------------------------------------------------------
// K2: softmax over normalized Gram (sum 4 slots), folded with Wp:
//   Mt[b][c=h*16+e][o] = sum_d Wp[o][h*16+d] * attn[b][h][d][e].  2 blocks.
// ---------------------------------------------------------------------------
__global__ __launch_bounds__(256) void k_attn(const float* __restrict__ rescale,
    const float* __restrict__ Wp, float* __restrict__ ws)
{
    __shared__ float sAtt[1024];        // [h][d][e]
    const int b = blockIdx.x, t = threadIdx.x;
    const int d = t >> 4, e = t & 15;
#pragma unroll
    for (int h = 0; h < 4; ++h) {
        float g = 0.f, nk2 = 0.f, nq2 = 0.f;
#pragma unroll
        for (int s = 0; s < 4; ++s) {
            g   += ws[WS_G + s*2048 + b*1024 + (h*16+d)*16 + e];
            nk2 += ws[WS_SSQ + s*256 + 128 + b*64 + h*16 + d];
            nq2 += ws[WS_SSQ + s*256 +   0 + b*64 + h*16 + e];
        }
        float nk = fmaxf(sqrtf(nk2), 1e-12f);
        float nq = fmaxf(sqrtf(nq2), 1e-12f);
        float val = g / (nk*nq) * rescale[h];
        float m = val;
        for (int off = 1; off < 16; off <<= 1) m = fmaxf(m, __shfl_xor(m, off, 16));
        float ev = expf(val - m);
        float s2 = ev;
        for (int off = 1; off < 16; off <<= 1) s2 += __shfl_xor(s2, off, 16);
        sAtt[h*256 + d*16 + e] = ev / s2;
    }
    __syncthreads();
    float* Mtb = ws + WS_M + (size_t)b*4096;
    for (int idx = t; idx < 4096; idx += 256) {
        const int c = idx >> 6, o = idx & 63, h = c >> 4, ee = c & 15;
        float acc = 0.f;
#pragma unroll
        for (int d2 = 0; d2 < 16; ++d2)
            acc = fmaf(Wp[o*64 + h*16 + d2], sAtt[h*256 + d2*16 + ee], acc);
        Mtb[c*64 + o] = acc;
    }
}

// ---------------------------------------------------------------------------
// K3: per 8x8 tile: dwconv5x5(m2 bf16 halo)+dwb -> sigmoid ->
//   vm = vm0(d_out)*(1+sig) -> out = Mt . vm + bp.
// ---------------------------------------------------------------------------
__global__ __launch_bounds__(256, 4) void k_final(
    const __hip_bfloat16* __restrict__ m2g, const float* __restrict__ wsM,
    const float* __restrict__ bp, const float* __restrict__ dw,
    const float* __restrict__ dwb, float* __restrict__ out)
{
    __shared__ unsigned short m2s[144*64];  // 18.4 KB bf16 halo (0 outside)
    __shared__ unsigned short Mtl[4096];    // 8 KB bf16 blocked-f4 [c4][o][u]
    __shared__ float s_vm[4][4][64];        // per-wave
    const int tid = threadIdx.x, lane = tid & 63, w = tid >> 6;
    const int bid = blockIdx.x;
    const int b = bid >> 10, tile = bid & 1023;
    const int y0 = (tile >> 5) * 8, x0 = (tile & 31) * 8;
    const int c = lane;

    const float* Msrc = wsM + (size_t)b*4096;
    for (int i = tid; i < 4096; i += 256) {
        const int o = (i >> 2) & 63, gc = (i >> 8) * 4 + (i & 3);
        Mtl[i] = f2bf(Msrc[gc*64 + o]);
    }
    for (int i2 = tid; i2 < 2304; i2 += 256) {
        const int pos = i2 >> 4, c4 = (i2 & 15) * 4;
        const int yy = pos / 12, xx = pos - yy*12;
        const int gy = y0 + yy - 2, gx = x0 + xx - 2;
        ushort4 us = make_ushort4(0, 0, 0, 0);
        if (gy >= 0 && gy < 256 && gx >= 0 && gx < 256)
            us = *(const ushort4*)&m2g[(((size_t)b*256 + gy)*256 + gx)*64 + c4];
        *(ushort4*)&m2s[pos*64 + c4] = us;
    }
    __syncthreads();

    const float dwbr = dwb[c], bpr = bp[c];
    float dwr[25];
#pragma unroll
    for (int k = 0; k < 25; ++k) dwr[k] = dw[c*25+k];

    for (int g = 0; g < 4; ++g) {
        const int p0 = w*16 + g*4;          // 4 consecutive px in one row
        const int py = p0 >> 3, px0 = p0 & 7;
        float acc[4] = {dwbr, dwbr, dwbr, dwbr};
#pragma unroll
        for (int ky = 0; ky < 5; ++ky) {
            const int rbase = ((py+ky)*12 + px0)*64 + c;
#pragma unroll
            for (int kx8 = 0; kx8 < 8; ++kx8) {
                const float tv = bf2f(m2s[rbase + kx8*64]);
#pragma unroll
                for (int j = 0; j < 4; ++j) {
                    const int kk = kx8 - j;
                    if (kk >= 0 && kk < 5)
                        acc[j] = fmaf(tv, dwr[ky*5 + kk], acc[j]);
                }
            }
        }
        size_t P[4];
#pragma unroll
        for (int j = 0; j < 4; ++j) {
            P[j] = (size_t)b*65536 + (size_t)(y0+py)*256 + (x0+px0+j);
            const float s = 1.f / (1.f + expf(-acc[j]));
            s_vm[w][j][c] = out[P[j]*64 + c] * (1.f + s);   // vm0 * (1+sig)
        }
        __builtin_amdgcn_wave_barrier();
        float oc[4] = {bpr, bpr, bpr, bpr};
        for (int c4 = 0; c4 < 16; ++c4) {
            float4 v4[4];
#pragma unroll
            for (int j = 0; j < 4; ++j)
                v4[j] = *(const float4*)&s_vm[w][j][c4*4];  // broadcast
            const ushort4 m4 = *(const ushort4*)&Mtl[c4*256 + lane*4];
            const float mf[4] = {bf2f(m4.x), bf2f(m4.y), bf2f(m4.z), bf2f(m4.w)};
#pragma unroll
            for (int u = 0; u < 4; ++u)
#pragma unroll
                for (int j = 0; j < 4; ++j)
                    oc[j] = fmaf((&v4[j].x)[u], mf[u], oc[j]);
        }
#pragma unroll
        for (int j = 0; j < 4; ++j)
            out[P[j]*64 + c] = oc[j];
        __builtin_amdgcn_wave_barrier();
    }
}

// ---------------------------------------------------------------------------
// K4 (last): PE branch dwconv3x3 -> gelu -> dwconv3x3, += d_out.
// xt and t1 bf16 in LDS; t1 outside image is ZERO (conv2 padding).
// ---------------------------------------------------------------------------
__global__ __launch_bounds__(256, 5) void k_pe(const float* __restrict__ x,
    const float* __restrict__ w1, const float* __restrict__ w2,
    float* __restrict__ out)
{
    __shared__ unsigned short xt[12*12*64];     // 18.4 KB bf16
    __shared__ unsigned short t1[10*10*64];     // 12.8 KB bf16
    const int tid = threadIdx.x;
    const int bid = blockIdx.x;
    const int b = bid >> 10, tile = bid & 1023;
    const int y0 = (tile >> 5) * 8, x0 = (tile & 31) * 8;
    const int c = tid & 63;
    float w1r[9], w2r[9];
#pragma unroll
    for (int k = 0; k < 9; ++k) { w1r[k] = w1[c*9+k]; w2r[k] = w2[c*9+k]; }

    for (int i = tid; i < 12*12*64; i += 256) {
        int yy = i / 768, xx = (i % 768) >> 6;
        int gy = y0 + yy - 2, gx = x0 + xx - 2;
        float v = 0.f;
        if (gy >= 0 && gy < 256 && gx >= 0 && gx < 256)
            v = x[(((size_t)b*256 + gy)*256 + gx)*64 + c];
        xt[i] = f2bf(v);
    }
    __syncthreads();
    for (int i = tid; i < 10*10*64; i += 256) {
        int yy = i / 640, xx = (i % 640) >> 6;
        int gy = y0 + yy - 1, gx = x0 + xx - 1;
        float val = 0.f;
        if (gy >= 0 && gy < 256 && gx >= 0 && gx < 256) {
            float acc = 0.f;
#pragma unroll
            for (int ky = 0; ky < 3; ++ky)
#pragma unroll
                for (int kx = 0; kx < 3; ++kx)
                    acc = fmaf(bf2f(xt[((yy+ky)*12 + xx+kx)*64 + c]),
                               w1r[ky*3+kx], acc);
            val = 0.5f * acc * (1.f + erff(acc * 0.70710678118654752f));
        }
        t1[i] = f2bf(val);
    }
    __syncthreads();
    for (int i = tid; i < 8*8*64; i += 256) {
        int yy = i / 512, xx = (i % 512) >> 6;
        float acc = 0.f;
#pragma unroll
        for (int ky = 0; ky < 3; ++ky)
#pragma unroll
            for (int kx = 0; kx < 3; ++kx)
                acc = fmaf(bf2f(t1[((yy+ky)*10 + xx+kx)*64 + c]),
                           w2r[ky*3+kx], acc);
        out[(((size_t)b*256 + y0+yy)*256 + x0+xx)*64 + c] += acc;
    }
}

extern "C" void kernel_launch(void* const* d_in, const int* in_sizes, int n_in,
                              void* d_out, int out_size, void* d_ws, size_t ws_size,
                              hipStream_t stream)
{
    const float* x    = (const float*)d_in[0];
    const float* mask = (const float*)d_in[1];
    const float* Wq   = (const float*)d_in[2];
    const float* Wk   = (const float*)d_in[3];
    const float* Wv   = (const float*)d_in[4];
    const float* resc = (const float*)d_in[5];
    const float* Wp   = (const float*)d_in[6];
    const float* bp   = (const float*)d_in[7];
    const float* mw1  = (const float*)d_in[8];
    const float* mb1  = (const float*)d_in[9];
    const float* mw2  = (const float*)d_in[10];
    const float* mb2  = (const float*)d_in[11];
    const float* mdw  = (const float*)d_in[12];
    const float* mdwb = (const float*)d_in[13];
    const float* pw1  = (const float*)d_in[14];
    const float* pw2  = (const float*)d_in[15];
    float* ws  = (float*)d_ws;
    unsigned short* wg = (unsigned short*)((char*)d_ws + WS_WSWZ_BYTE);
    __hip_bfloat16* m2 = (__hip_bfloat16*)((char*)d_ws + WS_M2_BYTE);
    float* out = (float*)d_out;

    hipMemsetAsync(ws, 0, (size_t)9216*sizeof(float), stream);   // G + ssq slots

    k_prep <<<80,   256, 0, stream>>>(Wq, Wk, Wv, mw1, mw2, wg);
    k_fused<<<512,  512, 0, stream>>>(x, mask, wg, mb1, mb2, ws, out, m2);
    k_attn <<<2,    256, 0, stream>>>(resc, Wp, ws);
    k_final<<<2048, 256, 0, stream>>>(m2, ws + WS_M, bp, mdw, mdwb, out);
    k_pe   <<<2048, 256, 0, stream>>>(x, pw1, pw2, out);
}

// Round 6
// 287.460 us; speedup vs baseline: 1.4695x; 1.0548x over previous
//
#include <hip/hip_runtime.h>
#include <hip/hip_bf16.h>
#include <math.h>

#define BB 2
#define NPIX 131072            // 2*256*256

// ws float header (4-slot accumulators)
#define WS_G    0              // [slot4][B][1024]  (G[c=h*16+d][e])
#define WS_SSQ  8192           // [slot4][2][B][64] (0=q,1=k)
#define WS_M    9216           // [B][4096] folded Wp*blockdiag(attn), transposed
#define WS_WSWZ_BYTE ((size_t)17408*4)            // 20480 ushort pre-swizzled weights (40 KB)
#define WS_M2_BYTE   (WS_WSWZ_BYTE + 40960)       // m2 bf16: NPIX*64*2 = 16.78 MB

typedef __attribute__((ext_vector_type(8))) short short8;
typedef __attribute__((ext_vector_type(4))) float f32x4;

__device__ __forceinline__ unsigned short f2bf(float f) {
    unsigned u = __float_as_uint(f);
    u += 0x7FFFu + ((u >> 16) & 1u);            // RNE
    return (unsigned short)(u >> 16);
}
__device__ __forceinline__ float bf2f(unsigned short s) {
    return __uint_as_float((unsigned)s << 16);
}
__device__ __forceinline__ void lds_fence() {
    __asm__ __volatile__("s_waitcnt lgkmcnt(0)" ::: "memory");
}

// ---------------------------------------------------------------------------
// K0: pre-swizzle the 5 weight matrices into MFMA B-frag order, bf16, in ws.
// Also zeroes the G/ssq accumulator header (replaces hipMemsetAsync launch).
// ---------------------------------------------------------------------------
__global__ __launch_bounds__(256) void k_prep(const float* __restrict__ Wq,
    const float* __restrict__ Wk, const float* __restrict__ Wv,
    const float* __restrict__ w1, const float* __restrict__ w2,
    unsigned short* __restrict__ wg, float* __restrict__ ws)
{
    const int i = blockIdx.x*256 + threadIdx.x;     // 80 blocks -> 20480
    if (i < 9216) ws[i] = 0.f;                      // zero G + ssq slots
    const int f = i >> 9, l = (i >> 3) & 63, j = i & 7;
    const int matot = f >> 1, kh = f & 1;
    const int mat = matot >> 2, ot = matot & 3;
    const int o = ot*16 + (l & 15);
    const int cc = kh*32 + ((l >> 4) & 3)*8 + j;
    const float* Wsrc[5] = {Wq, Wk, Wv, w1, w2};
    wg[i] = f2bf(Wsrc[mat][o*64 + cc]);
}

// ---------------------------------------------------------------------------
// K1 (MFMA, fused): EXACT round-0 structure (proven 74 us; the 512-thread and
// no-LDS-weight variants both regressed). 512 blocks x 256 thr, 256 px/block,
// 4 t-iters/wave. LDS = 40(wswz) + 17(scr) + 2(ssq) = 59.5 KB -> 2 blk/CU.
// __launch_bounds__(256,2): VGPR cap 128, body ~100 -> no spill (cap model:
// cap = 256/min_waves_arg; arg>=4 caps at <=64 and spills ~200MB. r1/r2/r5).
// ---------------------------------------------------------------------------
__global__ __launch_bounds__(256, 2) void k_fused(
    const float* __restrict__ x, const float* __restrict__ mask,
    const unsigned short* __restrict__ wg,
    const float* __restrict__ b1, const float* __restrict__ b2,
    float* __restrict__ ws, float* __restrict__ out,
    __hip_bfloat16* __restrict__ m2out)
{
    __shared__ unsigned short wswz[20480];          // 40 KB
    __shared__ unsigned short scr[4][2176];         // 4.25 KB per wave
    __shared__ float s_ssq[4][2][64];               // 2 KB
    const int tid = threadIdx.x, lane = tid & 63, w = tid >> 6;
    const int quad = lane >> 4, col = lane & 15;
    const int blk = blockIdx.x, b = blk >> 8, slot = blk & 3;

    for (int i = tid; i < 2560; i += 256)           // 40KB contiguous b128
        ((uint4*)wswz)[i] = ((const uint4*)wg)[i];
    __syncthreads();

    float b1v[4], b2v[4];
#pragma unroll
    for (int ot = 0; ot < 4; ++ot) {
        b1v[ot] = b1[ot*16 + col];
        b2v[ot] = b2[ot*16 + col];
    }

#define WFRAG(matot, kh) (*(const short8*)&wswz[(((matot)*2 + (kh))*64 + lane)*8])

    float accG[16];
#pragma unroll
    for (int e = 0; e < 16; ++e) accG[e] = 0.f;
    float ssq_q = 0.f, ssq_k = 0.f;
    const int hbase = lane & 48;
    unsigned short* S = scr[w];

    for (int t = 0; t < 4; ++t) {
        const int pbase = blk*256 + t*64 + w*16;

        // A-frags from global (fp32 -> bf16): A[m=col(px)][k=quad*8+j (+32kh)]
        short8 xA[2], mA[2];
        {
            const float* xs = x    + ((size_t)(pbase + col))*64 + quad*8;
            const float* ms = mask + ((size_t)(pbase + col))*64 + quad*8;
#pragma unroll
            for (int kh = 0; kh < 2; ++kh) {
                float4 a0 = *(const float4*)(xs + kh*32);
                float4 a1 = *(const float4*)(xs + kh*32 + 4);
                float4 b0 = *(const float4*)(ms + kh*32);
                float4 b1f = *(const float4*)(ms + kh*32 + 4);
#pragma unroll
                for (int j = 0; j < 4; ++j) {
                    xA[kh][j]   = (short)f2bf((&a0.x)[j]);
                    xA[kh][4+j] = (short)f2bf((&a1.x)[j]);
                    mA[kh][j]   = (short)f2bf((&b0.x)[j]);
                    mA[kh][4+j] = (short)f2bf((&b1f.x)[j]);
                }
            }
        }

        // Phase A: q,k -> S as ushort [mat][p][68]
#pragma unroll
        for (int mm = 0; mm < 2; ++mm) {
#pragma unroll
            for (int ot = 0; ot < 4; ++ot) {
                f32x4 a = {0.f, 0.f, 0.f, 0.f};
                a = __builtin_amdgcn_mfma_f32_16x16x32_bf16(xA[0], WFRAG(mm*4+ot,0), a, 0,0,0);
                a = __builtin_amdgcn_mfma_f32_16x16x32_bf16(xA[1], WFRAG(mm*4+ot,1), a, 0,0,0);
#pragma unroll
                for (int r = 0; r < 4; ++r)
                    S[mm*1088 + (quad*4+r)*68 + ot*16 + col] = f2bf(a[r]);
            }
        }
        __builtin_amdgcn_wave_barrier();
        // Gram + ssq (lane = channel c): G[c][e] += k[p][c]*q[p][(c&48)+e]
#pragma unroll
        for (int p = 0; p < 16; ++p) {
            const float kv = bf2f(S[1088 + p*68 + lane]);
            const float qo = bf2f(S[p*68 + lane]);
            ssq_k = fmaf(kv, kv, ssq_k);
            ssq_q = fmaf(qo, qo, ssq_q);
#pragma unroll
            for (int e4 = 0; e4 < 4; ++e4) {
                ushort4 qq = *(const ushort4*)&S[p*68 + hbase + e4*4];
                accG[e4*4+0] = fmaf(kv, bf2f(qq.x), accG[e4*4+0]);
                accG[e4*4+1] = fmaf(kv, bf2f(qq.y), accG[e4*4+1]);
                accG[e4*4+2] = fmaf(kv, bf2f(qq.z), accG[e4*4+2]);
                accG[e4*4+3] = fmaf(kv, bf2f(qq.w), accG[e4*4+3]);
            }
        }
        lds_fence();                    // Gram reads done before S reused

        // v, m1
        f32x4 vfr[4], m1fr[4];
#pragma unroll
        for (int ot = 0; ot < 4; ++ot) {
            f32x4 a = {0.f, 0.f, 0.f, 0.f};
            a = __builtin_amdgcn_mfma_f32_16x16x32_bf16(xA[0], WFRAG(8+ot,0), a, 0,0,0);
            a = __builtin_amdgcn_mfma_f32_16x16x32_bf16(xA[1], WFRAG(8+ot,1), a, 0,0,0);
            vfr[ot] = a;
        }
#pragma unroll
        for (int ot = 0; ot < 4; ++ot) {
            f32x4 a = {0.f, 0.f, 0.f, 0.f};
            a = __builtin_amdgcn_mfma_f32_16x16x32_bf16(mA[0], WFRAG(12+ot,0), a, 0,0,0);
            a = __builtin_amdgcn_mfma_f32_16x16x32_bf16(mA[1], WFRAG(12+ot,1), a, 0,0,0);
#pragma unroll
            for (int r = 0; r < 4; ++r) a[r] += b1v[ot];
            m1fr[ot] = a;
        }

        // Phase B: vm0 fp32 [16][66] in S, then coalesced 512B row stores
        float* vscr = (float*)S;
#pragma unroll
        for (int ot = 0; ot < 4; ++ot)
#pragma unroll
            for (int r = 0; r < 4; ++r)
                vscr[(quad*4+r)*66 + ot*16 + col] = vfr[ot][r] * m1fr[ot][r];
        __builtin_amdgcn_wave_barrier();
        {
            const int rb = lane >> 5, ci = (lane & 31)*2;
#pragma unroll
            for (int pp = 0; pp < 8; ++pp) {
                const int row = pp*2 + rb;
                float2 v2 = *(const float2*)&vscr[row*66 + ci];
                *(float2*)&out[((size_t)(pbase + row))*64 + ci] = v2;
            }
        }
        lds_fence();                    // vm0 reads done before S reused

        // Phase C: m1 bf16 [16][72] in S -> A-frags for m2
#pragma unroll
        for (int ot = 0; ot < 4; ++ot)
#pragma unroll
            for (int r = 0; r < 4; ++r)
                S[(quad*4+r)*72 + ot*16 + col] = f2bf(m1fr[ot][r]);
        __builtin_amdgcn_wave_barrier();
        short8 a2[2];
#pragma unroll
        for (int kh = 0; kh < 2; ++kh)
            a2[kh] = *(const short8*)&S[col*72 + kh*32 + quad*8];
        lds_fence();                    // a2 reads done before S overwritten

        // Phase D: m2 mfma, bf16 [16][72] in S, coalesced packed-uint stores
#pragma unroll
        for (int ot = 0; ot < 4; ++ot) {
            f32x4 a = {0.f, 0.f, 0.f, 0.f};
            a = __builtin_amdgcn_mfma_f32_16x16x32_bf16(a2[0], WFRAG(16+ot,0), a, 0,0,0);
            a = __builtin_amdgcn_mfma_f32_16x16x32_bf16(a2[1], WFRAG(16+ot,1), a, 0,0,0);
#pragma unroll
            for (int r = 0; r < 4; ++r)
                S[(quad*4+r)*72 + ot*16 + col] = f2bf(a[r] + b2v[ot]);
        }
        __builtin_amdgcn_wave_barrier();
        {
            unsigned short* m2u = (unsigned short*)m2out;
            const int rb = lane >> 5, ci = (lane & 31)*2;
#pragma unroll
            for (int pp = 0; pp < 8; ++pp) {
                const int row = pp*2 + rb;
                unsigned vv = *(const unsigned*)&S[row*72 + ci];
                *(unsigned*)&m2u[((size_t)(pbase + row))*64 + ci] = vv;
            }
        }
        lds_fence();                    // m2 reads done before next iter
    }

    __syncthreads();                    // all waves done with scr

    // two-phase block reduction of G (2048 floats in scr), layout [w2][e][lane]
    float* gr = (float*)&scr[0][0];
    if (w < 2) {
#pragma unroll
        for (int e = 0; e < 16; ++e) gr[w*1024 + e*64 + lane] = accG[e];
    }
    s_ssq[w][0][lane] = ssq_q;
    s_ssq[w][1][lane] = ssq_k;
    __syncthreads();
    if (w >= 2) {
#pragma unroll
        for (int e = 0; e < 16; ++e) gr[(w-2)*1024 + e*64 + lane] += accG[e];
    }
    __syncthreads();
    float* Gg = ws + WS_G + (size_t)slot*2048 + (size_t)b*1024;
    for (int idx = tid; idx < 1024; idx += 256) {
        const int e = idx >> 6, c = idx & 63;
        atomicAdd(&Gg[c*16 + e], gr[idx] + gr[1024 + idx]);
    }
    if (tid < 128) {
        const int which = tid >> 6, cidx = tid & 63;
        float s = s_ssq[0][which][cidx] + s_ssq[1][which][cidx]
                + s_ssq[2][which][cidx] + s_ssq[3][which][cidx];
        atomicAdd(ws + WS_SSQ + (size_t)slot*256 + which*128 + b*64 + cidx, s);
    }
#undef WFRAG
}

// ---------------------------------------------------------------------------
// K2: softmax over normalized Gram (sum 4 slots), folded with Wp:
//   Mt[b][c=h*16+e][o] = sum_d Wp[o][h*16+d] * attn[b][h][d][e].  2 blocks.
// ---------------------------------------------------------------------------
__global__ __launch_bounds__(256) void k_attn(const float* __restrict__ rescale,
    const float* __restrict__ Wp, float* __restrict__ ws)
{
    __shared__ float sAtt[1024];        // [h][d][e]
    const int b = blockIdx.x, t = threadIdx.x;
    const int d = t >> 4, e = t & 15;
#pragma unroll
    for (int h = 0; h < 4; ++h) {
        float g = 0.f, nk2 = 0.f, nq2 = 0.f;
#pragma unroll
        for (int s = 0; s < 4; ++s) {
            g   += ws[WS_G + s*2048 + b*1024 + (h*16+d)*16 + e];
            nk2 += ws[WS_SSQ + s*256 + 128 + b*64 + h*16 + d];
            nq2 += ws[WS_SSQ + s*256 +   0 + b*64 + h*16 + e];
        }
        float nk = fmaxf(sqrtf(nk2), 1e-12f);
        float nq = fmaxf(sqrtf(nq2), 1e-12f);
        float val = g / (nk*nq) * rescale[h];
        float m = val;
        for (int off = 1; off < 16; off <<= 1) m = fmaxf(m, __shfl_xor(m, off, 16));
        float ev = expf(val - m);
        float s2 = ev;
        for (int off = 1; off < 16; off <<= 1) s2 += __shfl_xor(s2, off, 16);
        sAtt[h*256 + d*16 + e] = ev / s2;
    }
    __syncthreads();
    float* Mtb = ws + WS_M + (size_t)b*4096;
    for (int idx = t; idx < 4096; idx += 256) {
        const int c = idx >> 6, o = idx & 63, h = c >> 4, ee = c & 15;
        float acc = 0.f;
#pragma unroll
        for (int d2 = 0; d2 < 16; ++d2)
            acc = fmaf(Wp[o*64 + h*16 + d2], sAtt[h*256 + d2*16 + ee], acc);
        Mtb[c*64 + o] = acc;
    }
}

// ---------------------------------------------------------------------------
// K3 (merged k_final + k_pe): per 8x8 tile:
//  Phase PE: dwconv3x3(x halo) -> gelu -> dwconv3x3 -> pe[4][4] in registers.
//  Phase F : dwconv5x5(m2 halo)+dwb -> sigmoid -> vm = vm0(out)*(1+sig)
//            -> out = Mt . vm + bp + pe   (single out write).
// Saves one full out read+write (67 MB) + one launch vs separate kernels.
// LDS phases alias one 31 KB buffer. __launch_bounds__(256,2): 128-VGPR cap
// (old k_final (256,4)=64-cap and k_pe (256,5)=51-cap likely both spilled:
// dwr[25]/w1r+w2r[18] bodies under caps — cap model from r1/r2/r5).
// ---------------------------------------------------------------------------
__global__ __launch_bounds__(256, 2) void k_fp(
    const float* __restrict__ x, const __hip_bfloat16* __restrict__ m2g,
    const float* __restrict__ wsM, const float* __restrict__ bp,
    const float* __restrict__ dw, const float* __restrict__ dwb,
    const float* __restrict__ pw1, const float* __restrict__ pw2,
    float* __restrict__ out)
{
    __shared__ __align__(16) char smem[31744];
    unsigned short* xt  = (unsigned short*)smem;            // 12*12*64 (PE)
    unsigned short* t1  = (unsigned short*)(smem + 18432);  // 10*10*64 (PE)
    unsigned short* m2s = (unsigned short*)smem;            // 144*64   (F)
    unsigned short* Mtl = (unsigned short*)(smem + 18432);  // 4096     (F)
    float*          svm = (float*)(smem + 18432 + 8192);    // [4][4][64] (F)
    const int tid = threadIdx.x, lane = tid & 63, w = tid >> 6;
    const int bid = blockIdx.x;
    const int b = bid >> 10, tile = bid & 1023;
    const int y0 = (tile >> 5) * 8, x0 = (tile & 31) * 8;
    const int c = lane;

    // ---------------- Phase PE ----------------
    float w1r[9], w2r[9];
#pragma unroll
    for (int k = 0; k < 9; ++k) { w1r[k] = pw1[c*9+k]; w2r[k] = pw2[c*9+k]; }

    for (int i = tid; i < 12*12*64; i += 256) {
        int yy = i / 768, xx = (i % 768) >> 6;
        int gy = y0 + yy - 2, gx = x0 + xx - 2;
        float v = 0.f;
        if (gy >= 0 && gy < 256 && gx >= 0 && gx < 256)
            v = x[(((size_t)b*256 + gy)*256 + gx)*64 + c];
        xt[i] = f2bf(v);
    }
    __syncthreads();
    for (int i = tid; i < 10*10*64; i += 256) {
        int yy = i / 640, xx = (i % 640) >> 6;
        int gy = y0 + yy - 1, gx = x0 + xx - 1;
        float val = 0.f;
        if (gy >= 0 && gy < 256 && gx >= 0 && gx < 256) {
            float acc = 0.f;
#pragma unroll
            for (int ky = 0; ky < 3; ++ky)
#pragma unroll
                for (int kx = 0; kx < 3; ++kx)
                    acc = fmaf(bf2f(xt[((yy+ky)*12 + xx+kx)*64 + c]),
                               w1r[ky*3+kx], acc);
            val = 0.5f * acc * (1.f + erff(acc * 0.70710678118654752f));
        }
        t1[i] = f2bf(val);
    }
    __syncthreads();

    float pe[4][4];                     // px mapping matches phase F (w,g,j)
#pragma unroll
    for (int g = 0; g < 4; ++g) {
        const int p0 = w*16 + g*4, py = p0 >> 3, px0 = p0 & 7;
#pragma unroll
        for (int j = 0; j < 4; ++j) {
            float acc = 0.f;
#pragma unroll
            for (int ky = 0; ky < 3; ++ky)
#pragma unroll
                for (int kx = 0; kx < 3; ++kx)
                    acc = fmaf(bf2f(t1[((py+ky)*10 + px0+j+kx)*64 + c]),
                               w2r[ky*3+kx], acc);
            pe[g][j] = acc;
        }
    }
    __syncthreads();                    // PE reads done before LDS realias

    // ---------------- Phase F ----------------
    const float* Msrc = wsM + (size_t)b*4096;
    for (int i = tid; i < 4096; i += 256) {
        const int o = (i >> 2) & 63, gc = (i >> 8) * 4 + (i & 3);
        Mtl[i] = f2bf(Msrc[gc*64 + o]);
    }
    for (int i2 = tid; i2 < 2304; i2 += 256) {
        const int pos = i2 >> 4, c4 = (i2 & 15) * 4;
        const int yy = pos / 12, xx = pos - yy*12;
        const int gy = y0 + yy - 2, gx = x0 + xx - 2;
        ushort4 us = make_ushort4(0, 0, 0, 0);
        if (gy >= 0 && gy < 256 && gx >= 0 && gx < 256)
            us = *(const ushort4*)&m2g[(((size_t)b*256 + gy)*256 + gx)*64 + c4];
        *(ushort4*)&m2s[pos*64 + c4] = us;
    }
    __syncthreads();

    const float dwbr = dwb[c], bpr = bp[c];
    float dwr[25];
#pragma unroll
    for (int k = 0; k < 25; ++k) dwr[k] = dw[c*25+k];

#pragma unroll
    for (int g = 0; g < 4; ++g) {
        const int p0 = w*16 + g*4;          // 4 consecutive px in one row
        const int py = p0 >> 3, px0 = p0 & 7;
        float acc[4] = {dwbr, dwbr, dwbr, dwbr};
#pragma unroll
        for (int ky = 0; ky < 5; ++ky) {
            const int rbase = ((py+ky)*12 + px0)*64 + c;
#pragma unroll
            for (int kx8 = 0; kx8 < 8; ++kx8) {
                const float tv = bf2f(m2s[rbase + kx8*64]);
#pragma unroll
                for (int j = 0; j < 4; ++j) {
                    const int kk = kx8 - j;
                    if (kk >= 0 && kk < 5)
                        acc[j] = fmaf(tv, dwr[ky*5 + kk], acc[j]);
                }
            }
        }
        size_t P[4];
#pragma unroll
        for (int j = 0; j < 4; ++j) {
            P[j] = (size_t)b*65536 + (size_t)(y0+py)*256 + (x0+px0+j);
            const float s = 1.f / (1.f + expf(-acc[j]));
            svm[(w*4 + j)*64 + c] = out[P[j]*64 + c] * (1.f + s);  // vm0*(1+sig)
        }
        __builtin_amdgcn_wave_barrier();
        float oc[4] = {bpr, bpr, bpr, bpr};
        for (int c4 = 0; c4 < 16; ++c4) {
            float4 v4[4];
#pragma unroll
            for (int j = 0; j < 4; ++j)
                v4[j] = *(const float4*)&svm[(w*4 + j)*64 + c4*4];  // broadcast
            const ushort4 m4 = *(const ushort4*)&Mtl[c4*256 + lane*4];
            const float mf[4] = {bf2f(m4.x), bf2f(m4.y), bf2f(m4.z), bf2f(m4.w)};
#pragma unroll
            for (int u = 0; u < 4; ++u)
#pragma unroll
                for (int j = 0; j < 4; ++j)
                    oc[j] = fmaf((&v4[j].x)[u], mf[u], oc[j]);
        }
#pragma unroll
        for (int j = 0; j < 4; ++j)
            out[P[j]*64 + c] = oc[j] + pe[g][j];
        __builtin_amdgcn_wave_barrier();
    }
}

extern "C" void kernel_launch(void* const* d_in, const int* in_sizes, int n_in,
                              void* d_out, int out_size, void* d_ws, size_t ws_size,
                              hipStream_t stream)
{
    const float* x    = (const float*)d_in[0];
    const float* mask = (const float*)d_in[1];
    const float* Wq   = (const float*)d_in[2];
    const float* Wk   = (const float*)d_in[3];
    const float* Wv   = (const float*)d_in[4];
    const float* resc = (const float*)d_in[5];
    const float* Wp   = (const float*)d_in[6];
    const float* bp   = (const float*)d_in[7];
    const float* mw1  = (const float*)d_in[8];
    const float* mb1  = (const float*)d_in[9];
    const float* mw2  = (const float*)d_in[10];
    const float* mb2  = (const float*)d_in[11];
    const float* mdw  = (const float*)d_in[12];
    const float* mdwb = (const float*)d_in[13];
    const float* pw1  = (const float*)d_in[14];
    const float* pw2  = (const float*)d_in[15];
    float* ws  = (float*)d_ws;
    unsigned short* wg = (unsigned short*)((char*)d_ws + WS_WSWZ_BYTE);
    __hip_bfloat16* m2 = (__hip_bfloat16*)((char*)d_ws + WS_M2_BYTE);
    float* out = (float*)d_out;

    k_prep <<<80,   256, 0, stream>>>(Wq, Wk, Wv, mw1, mw2, wg, ws);
    k_fused<<<512,  256, 0, stream>>>(x, mask, wg, mb1, mb2, ws, out, m2);
    k_attn <<<2,    256, 0, stream>>>(resc, Wp, ws);
    k_fp   <<<2048, 256, 0, stream>>>(x, m2, ws + WS_M, bp, mdw, mdwb,
                                      pw1, pw2, out);
}

// Round 7
// 286.510 us; speedup vs baseline: 1.4743x; 1.0033x over previous
//
#include <hip/hip_runtime.h>
#include <hip/hip_bf16.h>
#include <math.h>

#define BB 2
#define NPIX 131072            // 2*256*256

// ws float header (4-slot accumulators)
#define WS_G    0              // [slot4][B][1024]  (G[c=h*16+d][e])
#define WS_SSQ  8192           // [slot4][2][B][64] (0=q,1=k)
#define WS_M    9216           // [B][4096] folded Wp*blockdiag(attn), transposed
#define WS_WSWZ_BYTE ((size_t)17408*4)            // 20480 ushort pre-swizzled weights (40 KB)
#define WS_M2_BYTE   (WS_WSWZ_BYTE + 40960)       // m2 bf16: NPIX*64*2 = 16.78 MB

typedef __attribute__((ext_vector_type(8))) short short8;
typedef __attribute__((ext_vector_type(4))) float f32x4;

__device__ __forceinline__ unsigned short f2bf(float f) {
    unsigned u = __float_as_uint(f);
    u += 0x7FFFu + ((u >> 16) & 1u);            // RNE
    return (unsigned short)(u >> 16);
}
__device__ __forceinline__ float bf2f(unsigned short s) {
    return __uint_as_float((unsigned)s << 16);
}
__device__ __forceinline__ void lds_fence() {
    __asm__ __volatile__("s_waitcnt lgkmcnt(0)" ::: "memory");
}

// ---------------------------------------------------------------------------
// K0: pre-swizzle the 5 weight matrices into MFMA B-frag order, bf16, in ws.
// Also zeroes the G/ssq accumulator header (replaces hipMemsetAsync launch).
// ---------------------------------------------------------------------------
__global__ __launch_bounds__(256) void k_prep(const float* __restrict__ Wq,
    const float* __restrict__ Wk, const float* __restrict__ Wv,
    const float* __restrict__ w1, const float* __restrict__ w2,
    unsigned short* __restrict__ wg, float* __restrict__ ws)
{
    const int i = blockIdx.x*256 + threadIdx.x;     // 80 blocks -> 20480
    if (i < 9216) ws[i] = 0.f;                      // zero G + ssq slots
    const int f = i >> 9, l = (i >> 3) & 63, j = i & 7;
    const int matot = f >> 1, kh = f & 1;
    const int mat = matot >> 2, ot = matot & 3;
    const int o = ot*16 + (l & 15);
    const int cc = kh*32 + ((l >> 4) & 3)*8 + j;
    const float* Wsrc[5] = {Wq, Wk, Wv, w1, w2};
    wg[i] = f2bf(Wsrc[mat][o*64 + cc]);
}

// ---------------------------------------------------------------------------
// K1 (MFMA, fused): EXACT round-0 structure (proven 74 us). 512 blocks x 256
// thr, 256 px/block, 4 t-iters/wave. LDS = 40+17+2 = 59.5 KB -> 2 blk/CU.
// __launch_bounds__(256,2): VGPR cap 128, body ~100 -> no spill.
// ---------------------------------------------------------------------------
__global__ __launch_bounds__(256, 2) void k_fused(
    const float* __restrict__ x, const float* __restrict__ mask,
    const unsigned short* __restrict__ wg,
    const float* __restrict__ b1, const float* __restrict__ b2,
    float* __restrict__ ws, float* __restrict__ out,
    __hip_bfloat16* __restrict__ m2out)
{
    __shared__ unsigned short wswz[20480];          // 40 KB
    __shared__ unsigned short scr[4][2176];         // 4.25 KB per wave
    __shared__ float s_ssq[4][2][64];               // 2 KB
    const int tid = threadIdx.x, lane = tid & 63, w = tid >> 6;
    const int quad = lane >> 4, col = lane & 15;
    const int blk = blockIdx.x, b = blk >> 8, slot = blk & 3;

    for (int i = tid; i < 2560; i += 256)           // 40KB contiguous b128
        ((uint4*)wswz)[i] = ((const uint4*)wg)[i];
    __syncthreads();

    float b1v[4], b2v[4];
#pragma unroll
    for (int ot = 0; ot < 4; ++ot) {
        b1v[ot] = b1[ot*16 + col];
        b2v[ot] = b2[ot*16 + col];
    }

#define WFRAG(matot, kh) (*(const short8*)&wswz[(((matot)*2 + (kh))*64 + lane)*8])

    float accG[16];
#pragma unroll
    for (int e = 0; e < 16; ++e) accG[e] = 0.f;
    float ssq_q = 0.f, ssq_k = 0.f;
    const int hbase = lane & 48;
    unsigned short* S = scr[w];

    for (int t = 0; t < 4; ++t) {
        const int pbase = blk*256 + t*64 + w*16;

        // A-frags from global (fp32 -> bf16): A[m=col(px)][k=quad*8+j (+32kh)]
        short8 xA[2], mA[2];
        {
            const float* xs = x    + ((size_t)(pbase + col))*64 + quad*8;
            const float* ms = mask + ((size_t)(pbase + col))*64 + quad*8;
#pragma unroll
            for (int kh = 0; kh < 2; ++kh) {
                float4 a0 = *(const float4*)(xs + kh*32);
                float4 a1 = *(const float4*)(xs + kh*32 + 4);
                float4 b0 = *(const float4*)(ms + kh*32);
                float4 b1f = *(const float4*)(ms + kh*32 + 4);
#pragma unroll
                for (int j = 0; j < 4; ++j) {
                    xA[kh][j]   = (short)f2bf((&a0.x)[j]);
                    xA[kh][4+j] = (short)f2bf((&a1.x)[j]);
                    mA[kh][j]   = (short)f2bf((&b0.x)[j]);
                    mA[kh][4+j] = (short)f2bf((&b1f.x)[j]);
                }
            }
        }

        // Phase A: q,k -> S as ushort [mat][p][68]
#pragma unroll
        for (int mm = 0; mm < 2; ++mm) {
#pragma unroll
            for (int ot = 0; ot < 4; ++ot) {
                f32x4 a = {0.f, 0.f, 0.f, 0.f};
                a = __builtin_amdgcn_mfma_f32_16x16x32_bf16(xA[0], WFRAG(mm*4+ot,0), a, 0,0,0);
                a = __builtin_amdgcn_mfma_f32_16x16x32_bf16(xA[1], WFRAG(mm*4+ot,1), a, 0,0,0);
#pragma unroll
                for (int r = 0; r < 4; ++r)
                    S[mm*1088 + (quad*4+r)*68 + ot*16 + col] = f2bf(a[r]);
            }
        }
        __builtin_amdgcn_wave_barrier();
        // Gram + ssq (lane = channel c): G[c][e] += k[p][c]*q[p][(c&48)+e]
#pragma unroll
        for (int p = 0; p < 16; ++p) {
            const float kv = bf2f(S[1088 + p*68 + lane]);
            const float qo = bf2f(S[p*68 + lane]);
            ssq_k = fmaf(kv, kv, ssq_k);
            ssq_q = fmaf(qo, qo, ssq_q);
#pragma unroll
            for (int e4 = 0; e4 < 4; ++e4) {
                ushort4 qq = *(const ushort4*)&S[p*68 + hbase + e4*4];
                accG[e4*4+0] = fmaf(kv, bf2f(qq.x), accG[e4*4+0]);
                accG[e4*4+1] = fmaf(kv, bf2f(qq.y), accG[e4*4+1]);
                accG[e4*4+2] = fmaf(kv, bf2f(qq.z), accG[e4*4+2]);
                accG[e4*4+3] = fmaf(kv, bf2f(qq.w), accG[e4*4+3]);
            }
        }
        lds_fence();                    // Gram reads done before S reused

        // v, m1
        f32x4 vfr[4], m1fr[4];
#pragma unroll
        for (int ot = 0; ot < 4; ++ot) {
            f32x4 a = {0.f, 0.f, 0.f, 0.f};
            a = __builtin_amdgcn_mfma_f32_16x16x32_bf16(xA[0], WFRAG(8+ot,0), a, 0,0,0);
            a = __builtin_amdgcn_mfma_f32_16x16x32_bf16(xA[1], WFRAG(8+ot,1), a, 0,0,0);
            vfr[ot] = a;
        }
#pragma unroll
        for (int ot = 0; ot < 4; ++ot) {
            f32x4 a = {0.f, 0.f, 0.f, 0.f};
            a = __builtin_amdgcn_mfma_f32_16x16x32_bf16(mA[0], WFRAG(12+ot,0), a, 0,0,0);
            a = __builtin_amdgcn_mfma_f32_16x16x32_bf16(mA[1], WFRAG(12+ot,1), a, 0,0,0);
#pragma unroll
            for (int r = 0; r < 4; ++r) a[r] += b1v[ot];
            m1fr[ot] = a;
        }

        // Phase B: vm0 fp32 [16][66] in S, then coalesced 512B row stores
        float* vscr = (float*)S;
#pragma unroll
        for (int ot = 0; ot < 4; ++ot)
#pragma unroll
            for (int r = 0; r < 4; ++r)
                vscr[(quad*4+r)*66 + ot*16 + col] = vfr[ot][r] * m1fr[ot][r];
        __builtin_amdgcn_wave_barrier();
        {
            const int rb = lane >> 5, ci = (lane & 31)*2;
#pragma unroll
            for (int pp = 0; pp < 8; ++pp) {
                const int row = pp*2 + rb;
                float2 v2 = *(const float2*)&vscr[row*66 + ci];
                *(float2*)&out[((size_t)(pbase + row))*64 + ci] = v2;
            }
        }
        lds_fence();                    // vm0 reads done before S reused

        // Phase C: m1 bf16 [16][72] in S -> A-frags for m2
#pragma unroll
        for (int ot = 0; ot < 4; ++ot)
#pragma unroll
            for (int r = 0; r < 4; ++r)
                S[(quad*4+r)*72 + ot*16 + col] = f2bf(m1fr[ot][r]);
        __builtin_amdgcn_wave_barrier();
        short8 a2[2];
#pragma unroll
        for (int kh = 0; kh < 2; ++kh)
            a2[kh] = *(const short8*)&S[col*72 + kh*32 + quad*8];
        lds_fence();                    // a2 reads done before S overwritten

        // Phase D: m2 mfma, bf16 [16][72] in S, coalesced packed-uint stores
#pragma unroll
        for (int ot = 0; ot < 4; ++ot) {
            f32x4 a = {0.f, 0.f, 0.f, 0.f};
            a = __builtin_amdgcn_mfma_f32_16x16x32_bf16(a2[0], WFRAG(16+ot,0), a, 0,0,0);
            a = __builtin_amdgcn_mfma_f32_16x16x32_bf16(a2[1], WFRAG(16+ot,1), a, 0,0,0);
#pragma unroll
            for (int r = 0; r < 4; ++r)
                S[(quad*4+r)*72 + ot*16 + col] = f2bf(a[r] + b2v[ot]);
        }
        __builtin_amdgcn_wave_barrier();
        {
            unsigned short* m2u = (unsigned short*)m2out;
            const int rb = lane >> 5, ci = (lane & 31)*2;
#pragma unroll
            for (int pp = 0; pp < 8; ++pp) {
                const int row = pp*2 + rb;
                unsigned vv = *(const unsigned*)&S[row*72 + ci];
                *(unsigned*)&m2u[((size_t)(pbase + row))*64 + ci] = vv;
            }
        }
        lds_fence();                    // m2 reads done before next iter
    }

    __syncthreads();                    // all waves done with scr

    // two-phase block reduction of G (2048 floats in scr), layout [w2][e][lane]
    float* gr = (float*)&scr[0][0];
    if (w < 2) {
#pragma unroll
        for (int e = 0; e < 16; ++e) gr[w*1024 + e*64 + lane] = accG[e];
    }
    s_ssq[w][0][lane] = ssq_q;
    s_ssq[w][1][lane] = ssq_k;
    __syncthreads();
    if (w >= 2) {
#pragma unroll
        for (int e = 0; e < 16; ++e) gr[(w-2)*1024 + e*64 + lane] += accG[e];
    }
    __syncthreads();
    float* Gg = ws + WS_G + (size_t)slot*2048 + (size_t)b*1024;
    for (int idx = tid; idx < 1024; idx += 256) {
        const int e = idx >> 6, c = idx & 63;
        atomicAdd(&Gg[c*16 + e], gr[idx] + gr[1024 + idx]);
    }
    if (tid < 128) {
        const int which = tid >> 6, cidx = tid & 63;
        float s = s_ssq[0][which][cidx] + s_ssq[1][which][cidx]
                + s_ssq[2][which][cidx] + s_ssq[3][which][cidx];
        atomicAdd(ws + WS_SSQ + (size_t)slot*256 + which*128 + b*64 + cidx, s);
    }
#undef WFRAG
}

// ---------------------------------------------------------------------------
// K2: softmax over normalized Gram (sum 4 slots), folded with Wp:
//   Mt[b][c=h*16+e][o] = sum_d Wp[o][h*16+d] * attn[b][h][d][e].  2 blocks.
// ---------------------------------------------------------------------------
__global__ __launch_bounds__(256) void k_attn(const float* __restrict__ rescale,
    const float* __restrict__ Wp, float* __restrict__ ws)
{
    __shared__ float sAtt[1024];        // [h][d][e]
    const int b = blockIdx.x, t = threadIdx.x;
    const int d = t >> 4, e = t & 15;
#pragma unroll
    for (int h = 0; h < 4; ++h) {
        float g = 0.f, nk2 = 0.f, nq2 = 0.f;
#pragma unroll
        for (int s = 0; s < 4; ++s) {
            g   += ws[WS_G + s*2048 + b*1024 + (h*16+d)*16 + e];
            nk2 += ws[WS_SSQ + s*256 + 128 + b*64 + h*16 + d];
            nq2 += ws[WS_SSQ + s*256 +   0 + b*64 + h*16 + e];
        }
        float nk = fmaxf(sqrtf(nk2), 1e-12f);
        float nq = fmaxf(sqrtf(nq2), 1e-12f);
        float val = g / (nk*nq) * rescale[h];
        float m = val;
        for (int off = 1; off < 16; off <<= 1) m = fmaxf(m, __shfl_xor(m, off, 16));
        float ev = expf(val - m);
        float s2 = ev;
        for (int off = 1; off < 16; off <<= 1) s2 += __shfl_xor(s2, off, 16);
        sAtt[h*256 + d*16 + e] = ev / s2;
    }
    __syncthreads();
    float* Mtb = ws + WS_M + (size_t)b*4096;
    for (int idx = t; idx < 4096; idx += 256) {
        const int c = idx >> 6, o = idx & 63, h = c >> 4, ee = c & 15;
        float acc = 0.f;
#pragma unroll
        for (int d2 = 0; d2 < 16; ++d2)
            acc = fmaf(Wp[o*64 + h*16 + d2], sAtt[h*256 + d2*16 + ee], acc);
        Mtb[c*64 + o] = acc;
    }
}

// ---------------------------------------------------------------------------
// K3 (merged final+pe, MFMA matmul): per 8x8 tile:
//  Phase PE: dwconv3x3(x halo) -> gelu -> dwconv3x3 -> pe[4][4] regs.
//  Phase F : dwconv5x5(m2 halo)+dwb -> sigmoid -> vm = vm0*(1+sig) -> vmL bf16
//            -> out = MFMA(vm, Mt) + bp + pe.
// r6 counters: VALUBusy 66%, MfmaUtil 0 -> the 64x64x64 per-tile matmul
// (1024 scalar FMA/thread) moves to 8 MFMA/wave. Frag layouts mirror k_fused.
// LDS 40448B (peL aliases dead m2s after dwconv) -> 4 blocks/CU.
// ---------------------------------------------------------------------------
__global__ __launch_bounds__(256, 2) void k_fp(
    const float* __restrict__ x, const __hip_bfloat16* __restrict__ m2g,
    const float* __restrict__ wsM, const float* __restrict__ bp,
    const float* __restrict__ dw, const float* __restrict__ dwb,
    const float* __restrict__ pw1, const float* __restrict__ pw2,
    float* __restrict__ out)
{
    __shared__ __align__(16) char smem[40448];
    unsigned short* xt  = (unsigned short*)smem;            // PE: 12*12*64 (18432B)
    unsigned short* t1  = (unsigned short*)(smem + 18432);  // PE: 10*10*64 (12800B)
    unsigned short* m2s = (unsigned short*)smem;            // F:  144*64   (18432B)
    unsigned short* MtB = (unsigned short*)(smem + 18432);  // F:  4096     (8192B)
    unsigned short* vmL = (unsigned short*)(smem + 31232);  // F:  [64][72] (9216B)
    unsigned short* peL = (unsigned short*)smem;            // F late: [64][72], aliases m2s
    const int tid = threadIdx.x, lane = tid & 63, w = tid >> 6;
    const int quad = lane >> 4, col = lane & 15;
    const int bid = blockIdx.x;
    const int b = bid >> 10, tile = bid & 1023;
    const int y0 = (tile >> 5) * 8, x0 = (tile & 31) * 8;
    const int c = lane;

    // ---------------- Phase PE ----------------
    float w1r[9], w2r[9];
#pragma unroll
    for (int k = 0; k < 9; ++k) { w1r[k] = pw1[c*9+k]; w2r[k] = pw2[c*9+k]; }

    for (int i = tid; i < 12*12*64; i += 256) {
        int yy = i / 768, xx = (i % 768) >> 6;
        int gy = y0 + yy - 2, gx = x0 + xx - 2;
        float v = 0.f;
        if (gy >= 0 && gy < 256 && gx >= 0 && gx < 256)
            v = x[(((size_t)b*256 + gy)*256 + gx)*64 + c];
        xt[i] = f2bf(v);
    }
    __syncthreads();
    for (int i = tid; i < 10*10*64; i += 256) {
        int yy = i / 640, xx = (i % 640) >> 6;
        int gy = y0 + yy - 1, gx = x0 + xx - 1;
        float val = 0.f;
        if (gy >= 0 && gy < 256 && gx >= 0 && gx < 256) {
            float acc = 0.f;
#pragma unroll
            for (int ky = 0; ky < 3; ++ky)
#pragma unroll
                for (int kx = 0; kx < 3; ++kx)
                    acc = fmaf(bf2f(xt[((yy+ky)*12 + xx+kx)*64 + c]),
                               w1r[ky*3+kx], acc);
            val = 0.5f * acc * (1.f + erff(acc * 0.70710678118654752f));
        }
        t1[i] = f2bf(val);
    }
    __syncthreads();

    float pe[4][4];                     // (g,j): px = w*16+g*4+j, channel c
#pragma unroll
    for (int g = 0; g < 4; ++g) {
        const int p0 = w*16 + g*4, py = p0 >> 3, px0 = p0 & 7;
#pragma unroll
        for (int j = 0; j < 4; ++j) {
            float acc = 0.f;
#pragma unroll
            for (int ky = 0; ky < 3; ++ky)
#pragma unroll
                for (int kx = 0; kx < 3; ++kx)
                    acc = fmaf(bf2f(t1[((py+ky)*10 + px0+j+kx)*64 + c]),
                               w2r[ky*3+kx], acc);
            pe[g][j] = acc;
        }
    }
    __syncthreads();                    // PE reads done before LDS realias

    // ---------------- Phase F ----------------
    // Mt as MFMA B-frags: MtB[((ot*2+kh)*64+l)*8+j] = Mt[kh*32+((l>>4)&3)*8+j][ot*16+(l&15)]
    const float* Msrc = wsM + (size_t)b*4096;
    for (int i = tid; i < 4096; i += 256) {
        const int f = i >> 9, l = (i >> 3) & 63, j = i & 7;
        const int ot = f >> 1, kh = f & 1;
        MtB[i] = f2bf(Msrc[(kh*32 + ((l >> 4) & 3)*8 + j)*64 + ot*16 + (l & 15)]);
    }
    for (int i2 = tid; i2 < 2304; i2 += 256) {
        const int pos = i2 >> 4, c4 = (i2 & 15) * 4;
        const int yy = pos / 12, xx = pos - yy*12;
        const int gy = y0 + yy - 2, gx = x0 + xx - 2;
        ushort4 us = make_ushort4(0, 0, 0, 0);
        if (gy >= 0 && gy < 256 && gx >= 0 && gx < 256)
            us = *(const ushort4*)&m2g[(((size_t)b*256 + gy)*256 + gx)*64 + c4];
        *(ushort4*)&m2s[pos*64 + c4] = us;
    }
    __syncthreads();

    const float dwbr = dwb[c];
    float dwr[25];
#pragma unroll
    for (int k = 0; k < 25; ++k) dwr[k] = dw[c*25+k];

#pragma unroll
    for (int g = 0; g < 4; ++g) {
        const int p0 = w*16 + g*4;          // 4 consecutive px in one row
        const int py = p0 >> 3, px0 = p0 & 7;
        float acc[4] = {dwbr, dwbr, dwbr, dwbr};
#pragma unroll
        for (int ky = 0; ky < 5; ++ky) {
            const int rbase = ((py+ky)*12 + px0)*64 + c;
#pragma unroll
            for (int kx8 = 0; kx8 < 8; ++kx8) {
                const float tv = bf2f(m2s[rbase + kx8*64]);
#pragma unroll
                for (int j = 0; j < 4; ++j) {
                    const int kk = kx8 - j;
                    if (kk >= 0 && kk < 5)
                        acc[j] = fmaf(tv, dwr[ky*5 + kk], acc[j]);
                }
            }
        }
#pragma unroll
        for (int j = 0; j < 4; ++j) {
            const size_t P = (size_t)b*65536 + (size_t)(y0+py)*256 + (x0+px0+j);
            const float s = 1.f / (1.f + expf(-acc[j]));
            vmL[(p0 + j)*72 + c] = f2bf(out[P*64 + c] * (1.f + s));  // vm bf16
        }
    }
    __syncthreads();                    // all m2s reads + vmL writes complete

    // pe -> LDS (aliases dead m2s) in [px][c] layout for C-layout epilogue
#pragma unroll
    for (int g = 0; g < 4; ++g)
#pragma unroll
        for (int j = 0; j < 4; ++j)
            peL[(w*16 + g*4 + j)*72 + c] = f2bf(pe[g][j]);
    __builtin_amdgcn_wave_barrier();
    lds_fence();                        // wave-local peL/vmL visible

    // A-frags: A[m=col(px)][k=quad*8+j+32kh] from vmL
    short8 aV[2];
#pragma unroll
    for (int kh = 0; kh < 2; ++kh)
        aV[kh] = *(const short8*)&vmL[(w*16 + col)*72 + kh*32 + quad*8];
    float bpv[4];
#pragma unroll
    for (int ot = 0; ot < 4; ++ot) bpv[ot] = bp[ot*16 + col];

#pragma unroll
    for (int ot = 0; ot < 4; ++ot) {
        f32x4 a = {0.f, 0.f, 0.f, 0.f};
        a = __builtin_amdgcn_mfma_f32_16x16x32_bf16(aV[0],
                *(const short8*)&MtB[((ot*2+0)*64 + lane)*8], a, 0,0,0);
        a = __builtin_amdgcn_mfma_f32_16x16x32_bf16(aV[1],
                *(const short8*)&MtB[((ot*2+1)*64 + lane)*8], a, 0,0,0);
#pragma unroll
        for (int r = 0; r < 4; ++r) {
            const int pl = w*16 + quad*4 + r;       // C row = px in tile
            const int gy = y0 + (pl >> 3), gx = x0 + (pl & 7);
            out[(((size_t)b*256 + gy)*256 + gx)*64 + ot*16 + col] =
                a[r] + bpv[ot] + bf2f(peL[pl*72 + ot*16 + col]);
        }
    }
}

extern "C" void kernel_launch(void* const* d_in, const int* in_sizes, int n_in,
                              void* d_out, int out_size, void* d_ws, size_t ws_size,
                              hipStream_t stream)
{
    const float* x    = (const float*)d_in[0];
    const float* mask = (const float*)d_in[1];
    const float* Wq   = (const float*)d_in[2];
    const float* Wk   = (const float*)d_in[3];
    const float* Wv   = (const float*)d_in[4];
    const float* resc = (const float*)d_in[5];
    const float* Wp   = (const float*)d_in[6];
    const float* bp   = (const float*)d_in[7];
    const float* mw1  = (const float*)d_in[8];
    const float* mb1  = (const float*)d_in[9];
    const float* mw2  = (const float*)d_in[10];
    const float* mb2  = (const float*)d_in[11];
    const float* mdw  = (const float*)d_in[12];
    const float* mdwb = (const float*)d_in[13];
    const float* pw1  = (const float*)d_in[14];
    const float* pw2  = (const float*)d_in[15];
    float* ws  = (float*)d_ws;
    unsigned short* wg = (unsigned short*)((char*)d_ws + WS_WSWZ_BYTE);
    __hip_bfloat16* m2 = (__hip_bfloat16*)((char*)d_ws + WS_M2_BYTE);
    float* out = (float*)d_out;

    k_prep <<<80,   256, 0, stream>>>(Wq, Wk, Wv, mw1, mw2, wg, ws);
    k_fused<<<512,  256, 0, stream>>>(x, mask, wg, mb1, mb2, ws, out, m2);
    k_attn <<<2,    256, 0, stream>>>(resc, Wp, ws);
    k_fp   <<<2048, 256, 0, stream>>>(x, m2, ws + WS_M, bp, mdw, mdwb,
                                      pw1, pw2, out);
}

// Round 8
// 279.884 us; speedup vs baseline: 1.5092x; 1.0237x over previous
//
#include <hip/hip_runtime.h>
#include <hip/hip_bf16.h>
#include <math.h>

#define BB 2
#define NPIX 131072            // 2*256*256

// ws float header (4-slot accumulators)
#define WS_G    0              // [slot4][B][1024]  (G[c=h*16+d][e])
#define WS_SSQ  8192           // [slot4][2][B][64] (0=q,1=k)
#define WS_M    9216           // [B][4096] folded Wp*blockdiag(attn), transposed
#define WS_WSWZ_BYTE ((size_t)17408*4)            // 20480 ushort pre-swizzled weights (40 KB)
#define WS_M2_BYTE   (WS_WSWZ_BYTE + 40960)       // m2 bf16: NPIX*64*2 = 16.78 MB

typedef __attribute__((ext_vector_type(8))) short short8;
typedef __attribute__((ext_vector_type(4))) float f32x4;

__device__ __forceinline__ unsigned short f2bf(float f) {
    unsigned u = __float_as_uint(f);
    u += 0x7FFFu + ((u >> 16) & 1u);            // RNE
    return (unsigned short)(u >> 16);
}
__device__ __forceinline__ float bf2f(unsigned short s) {
    return __uint_as_float((unsigned)s << 16);
}
__device__ __forceinline__ void lds_fence() {
    __asm__ __volatile__("s_waitcnt lgkmcnt(0)" ::: "memory");
}
// fast transcendentals (r7: libm erff/expf ~25-30% of k_fp VALU issue).
// sigmoid via v_exp+v_rcp (~5 insts); tanh-GELU == x*sigmoid(1.59577(x+c x^3))
// (|err| vs erf-GELU <= 3e-4, scaled by pe_w2 L1 ~0.18 -> <=5e-5 in out).
__device__ __forceinline__ float fast_sigmoid(float a) {
    return __builtin_amdgcn_rcpf(1.f + __expf(-a));
}
__device__ __forceinline__ float fast_gelu(float x) {
    float y = 1.5957691216057308f * fmaf(0.044715f * x, x * x, x);
    return x * fast_sigmoid(y);
}

// ---------------------------------------------------------------------------
// K0: pre-swizzle the 5 weight matrices into MFMA B-frag order, bf16, in ws.
// Also zeroes the G/ssq accumulator header (replaces hipMemsetAsync launch).
// ---------------------------------------------------------------------------
__global__ __launch_bounds__(256) void k_prep(const float* __restrict__ Wq,
    const float* __restrict__ Wk, const float* __restrict__ Wv,
    const float* __restrict__ w1, const float* __restrict__ w2,
    unsigned short* __restrict__ wg, float* __restrict__ ws)
{
    const int i = blockIdx.x*256 + threadIdx.x;     // 80 blocks -> 20480
    if (i < 9216) ws[i] = 0.f;                      // zero G + ssq slots
    const int f = i >> 9, l = (i >> 3) & 63, j = i & 7;
    const int matot = f >> 1, kh = f & 1;
    const int mat = matot >> 2, ot = matot & 3;
    const int o = ot*16 + (l & 15);
    const int cc = kh*32 + ((l >> 4) & 3)*8 + j;
    const float* Wsrc[5] = {Wq, Wk, Wv, w1, w2};
    wg[i] = f2bf(Wsrc[mat][o*64 + cc]);
}

// ---------------------------------------------------------------------------
// K1 (MFMA, fused): EXACT round-0 structure (proven 74 us). 512 blocks x 256
// thr, 256 px/block, 4 t-iters/wave. LDS = 40+17+2 = 59.5 KB -> 2 blk/CU.
// __launch_bounds__(256,2): VGPR cap 128, body ~100 -> no spill.
// ---------------------------------------------------------------------------
__global__ __launch_bounds__(256, 2) void k_fused(
    const float* __restrict__ x, const float* __restrict__ mask,
    const unsigned short* __restrict__ wg,
    const float* __restrict__ b1, const float* __restrict__ b2,
    float* __restrict__ ws, float* __restrict__ out,
    __hip_bfloat16* __restrict__ m2out)
{
    __shared__ unsigned short wswz[20480];          // 40 KB
    __shared__ unsigned short scr[4][2176];         // 4.25 KB per wave
    __shared__ float s_ssq[4][2][64];               // 2 KB
    const int tid = threadIdx.x, lane = tid & 63, w = tid >> 6;
    const int quad = lane >> 4, col = lane & 15;
    const int blk = blockIdx.x, b = blk >> 8, slot = blk & 3;

    for (int i = tid; i < 2560; i += 256)           // 40KB contiguous b128
        ((uint4*)wswz)[i] = ((const uint4*)wg)[i];
    __syncthreads();

    float b1v[4], b2v[4];
#pragma unroll
    for (int ot = 0; ot < 4; ++ot) {
        b1v[ot] = b1[ot*16 + col];
        b2v[ot] = b2[ot*16 + col];
    }

#define WFRAG(matot, kh) (*(const short8*)&wswz[(((matot)*2 + (kh))*64 + lane)*8])

    float accG[16];
#pragma unroll
    for (int e = 0; e < 16; ++e) accG[e] = 0.f;
    float ssq_q = 0.f, ssq_k = 0.f;
    const int hbase = lane & 48;
    unsigned short* S = scr[w];

    for (int t = 0; t < 4; ++t) {
        const int pbase = blk*256 + t*64 + w*16;

        // A-frags from global (fp32 -> bf16): A[m=col(px)][k=quad*8+j (+32kh)]
        short8 xA[2], mA[2];
        {
            const float* xs = x    + ((size_t)(pbase + col))*64 + quad*8;
            const float* ms = mask + ((size_t)(pbase + col))*64 + quad*8;
#pragma unroll
            for (int kh = 0; kh < 2; ++kh) {
                float4 a0 = *(const float4*)(xs + kh*32);
                float4 a1 = *(const float4*)(xs + kh*32 + 4);
                float4 b0 = *(const float4*)(ms + kh*32);
                float4 b1f = *(const float4*)(ms + kh*32 + 4);
#pragma unroll
                for (int j = 0; j < 4; ++j) {
                    xA[kh][j]   = (short)f2bf((&a0.x)[j]);
                    xA[kh][4+j] = (short)f2bf((&a1.x)[j]);
                    mA[kh][j]   = (short)f2bf((&b0.x)[j]);
                    mA[kh][4+j] = (short)f2bf((&b1f.x)[j]);
                }
            }
        }

        // Phase A: q,k -> S as ushort [mat][p][68]
#pragma unroll
        for (int mm = 0; mm < 2; ++mm) {
#pragma unroll
            for (int ot = 0; ot < 4; ++ot) {
                f32x4 a = {0.f, 0.f, 0.f, 0.f};
                a = __builtin_amdgcn_mfma_f32_16x16x32_bf16(xA[0], WFRAG(mm*4+ot,0), a, 0,0,0);
                a = __builtin_amdgcn_mfma_f32_16x16x32_bf16(xA[1], WFRAG(mm*4+ot,1), a, 0,0,0);
#pragma unroll
                for (int r = 0; r < 4; ++r)
                    S[mm*1088 + (quad*4+r)*68 + ot*16 + col] = f2bf(a[r]);
            }
        }
        __builtin_amdgcn_wave_barrier();
        // Gram + ssq (lane = channel c): G[c][e] += k[p][c]*q[p][(c&48)+e]
#pragma unroll
        for (int p = 0; p < 16; ++p) {
            const float kv = bf2f(S[1088 + p*68 + lane]);
            const float qo = bf2f(S[p*68 + lane]);
            ssq_k = fmaf(kv, kv, ssq_k);
            ssq_q = fmaf(qo, qo, ssq_q);
#pragma unroll
            for (int e4 = 0; e4 < 4; ++e4) {
                ushort4 qq = *(const ushort4*)&S[p*68 + hbase + e4*4];
                accG[e4*4+0] = fmaf(kv, bf2f(qq.x), accG[e4*4+0]);
                accG[e4*4+1] = fmaf(kv, bf2f(qq.y), accG[e4*4+1]);
                accG[e4*4+2] = fmaf(kv, bf2f(qq.z), accG[e4*4+2]);
                accG[e4*4+3] = fmaf(kv, bf2f(qq.w), accG[e4*4+3]);
            }
        }
        lds_fence();                    // Gram reads done before S reused

        // v, m1
        f32x4 vfr[4], m1fr[4];
#pragma unroll
        for (int ot = 0; ot < 4; ++ot) {
            f32x4 a = {0.f, 0.f, 0.f, 0.f};
            a = __builtin_amdgcn_mfma_f32_16x16x32_bf16(xA[0], WFRAG(8+ot,0), a, 0,0,0);
            a = __builtin_amdgcn_mfma_f32_16x16x32_bf16(xA[1], WFRAG(8+ot,1), a, 0,0,0);
            vfr[ot] = a;
        }
#pragma unroll
        for (int ot = 0; ot < 4; ++ot) {
            f32x4 a = {0.f, 0.f, 0.f, 0.f};
            a = __builtin_amdgcn_mfma_f32_16x16x32_bf16(mA[0], WFRAG(12+ot,0), a, 0,0,0);
            a = __builtin_amdgcn_mfma_f32_16x16x32_bf16(mA[1], WFRAG(12+ot,1), a, 0,0,0);
#pragma unroll
            for (int r = 0; r < 4; ++r) a[r] += b1v[ot];
            m1fr[ot] = a;
        }

        // Phase B: vm0 fp32 [16][66] in S, then coalesced 512B row stores
        float* vscr = (float*)S;
#pragma unroll
        for (int ot = 0; ot < 4; ++ot)
#pragma unroll
            for (int r = 0; r < 4; ++r)
                vscr[(quad*4+r)*66 + ot*16 + col] = vfr[ot][r] * m1fr[ot][r];
        __builtin_amdgcn_wave_barrier();
        {
            const int rb = lane >> 5, ci = (lane & 31)*2;
#pragma unroll
            for (int pp = 0; pp < 8; ++pp) {
                const int row = pp*2 + rb;
                float2 v2 = *(const float2*)&vscr[row*66 + ci];
                *(float2*)&out[((size_t)(pbase + row))*64 + ci] = v2;
            }
        }
        lds_fence();                    // vm0 reads done before S reused

        // Phase C: m1 bf16 [16][72] in S -> A-frags for m2
#pragma unroll
        for (int ot = 0; ot < 4; ++ot)
#pragma unroll
            for (int r = 0; r < 4; ++r)
                S[(quad*4+r)*72 + ot*16 + col] = f2bf(m1fr[ot][r]);
        __builtin_amdgcn_wave_barrier();
        short8 a2[2];
#pragma unroll
        for (int kh = 0; kh < 2; ++kh)
            a2[kh] = *(const short8*)&S[col*72 + kh*32 + quad*8];
        lds_fence();                    // a2 reads done before S overwritten

        // Phase D: m2 mfma, bf16 [16][72] in S, coalesced packed-uint stores
#pragma unroll
        for (int ot = 0; ot < 4; ++ot) {
            f32x4 a = {0.f, 0.f, 0.f, 0.f};
            a = __builtin_amdgcn_mfma_f32_16x16x32_bf16(a2[0], WFRAG(16+ot,0), a, 0,0,0);
            a = __builtin_amdgcn_mfma_f32_16x16x32_bf16(a2[1], WFRAG(16+ot,1), a, 0,0,0);
#pragma unroll
            for (int r = 0; r < 4; ++r)
                S[(quad*4+r)*72 + ot*16 + col] = f2bf(a[r] + b2v[ot]);
        }
        __builtin_amdgcn_wave_barrier();
        {
            unsigned short* m2u = (unsigned short*)m2out;
            const int rb = lane >> 5, ci = (lane & 31)*2;
#pragma unroll
            for (int pp = 0; pp < 8; ++pp) {
                const int row = pp*2 + rb;
                unsigned vv = *(const unsigned*)&S[row*72 + ci];
                *(unsigned*)&m2u[((size_t)(pbase + row))*64 + ci] = vv;
            }
        }
        lds_fence();                    // m2 reads done before next iter
    }

    __syncthreads();                    // all waves done with scr

    // two-phase block reduction of G (2048 floats in scr), layout [w2][e][lane]
    float* gr = (float*)&scr[0][0];
    if (w < 2) {
#pragma unroll
        for (int e = 0; e < 16; ++e) gr[w*1024 + e*64 + lane] = accG[e];
    }
    s_ssq[w][0][lane] = ssq_q;
    s_ssq[w][1][lane] = ssq_k;
    __syncthreads();
    if (w >= 2) {
#pragma unroll
        for (int e = 0; e < 16; ++e) gr[(w-2)*1024 + e*64 + lane] += accG[e];
    }
    __syncthreads();
    float* Gg = ws + WS_G + (size_t)slot*2048 + (size_t)b*1024;
    for (int idx = tid; idx < 1024; idx += 256) {
        const int e = idx >> 6, c = idx & 63;
        atomicAdd(&Gg[c*16 + e], gr[idx] + gr[1024 + idx]);
    }
    if (tid < 128) {
        const int which = tid >> 6, cidx = tid & 63;
        float s = s_ssq[0][which][cidx] + s_ssq[1][which][cidx]
                + s_ssq[2][which][cidx] + s_ssq[3][which][cidx];
        atomicAdd(ws + WS_SSQ + (size_t)slot*256 + which*128 + b*64 + cidx, s);
    }
#undef WFRAG
}

// ---------------------------------------------------------------------------
// K2: softmax over normalized Gram (sum 4 slots), folded with Wp:
//   Mt[b][c=h*16+e][o] = sum_d Wp[o][h*16+d] * attn[b][h][d][e].  2 blocks.
// ---------------------------------------------------------------------------
__global__ __launch_bounds__(256) void k_attn(const float* __restrict__ rescale,
    const float* __restrict__ Wp, float* __restrict__ ws)
{
    __shared__ float sAtt[1024];        // [h][d][e]
    const int b = blockIdx.x, t = threadIdx.x;
    const int d = t >> 4, e = t & 15;
#pragma unroll
    for (int h = 0; h < 4; ++h) {
        float g = 0.f, nk2 = 0.f, nq2 = 0.f;
#pragma unroll
        for (int s = 0; s < 4; ++s) {
            g   += ws[WS_G + s*2048 + b*1024 + (h*16+d)*16 + e];
            nk2 += ws[WS_SSQ + s*256 + 128 + b*64 + h*16 + d];
            nq2 += ws[WS_SSQ + s*256 +   0 + b*64 + h*16 + e];
        }
        float nk = fmaxf(sqrtf(nk2), 1e-12f);
        float nq = fmaxf(sqrtf(nq2), 1e-12f);
        float val = g / (nk*nq) * rescale[h];
        float m = val;
        for (int off = 1; off < 16; off <<= 1) m = fmaxf(m, __shfl_xor(m, off, 16));
        float ev = expf(val - m);
        float s2 = ev;
        for (int off = 1; off < 16; off <<= 1) s2 += __shfl_xor(s2, off, 16);
        sAtt[h*256 + d*16 + e] = ev / s2;
    }
    __syncthreads();
    float* Mtb = ws + WS_M + (size_t)b*4096;
    for (int idx = t; idx < 4096; idx += 256) {
        const int c = idx >> 6, o = idx & 63, h = c >> 4, ee = c & 15;
        float acc = 0.f;
#pragma unroll
        for (int d2 = 0; d2 < 16; ++d2)
            acc = fmaf(Wp[o*64 + h*16 + d2], sAtt[h*256 + d2*16 + ee], acc);
        Mtb[c*64 + o] = acc;
    }
}

// ---------------------------------------------------------------------------
// K3 (merged final+pe, MFMA matmul, fast transcendentals): per 8x8 tile:
//  Phase PE: dwconv3x3(x halo) -> fast_gelu -> dwconv3x3 -> pe[4][4] regs.
//  Phase F : dwconv5x5(m2 halo)+dwb -> fast_sigmoid -> vm = vm0*(1+sig)
//            -> out = MFMA(vm, Mt) + bp + pe.
// r7 counters: VALUBusy 55%, VGPR 84 (4 waves/SIMD cap), LDS 40448 (4 blk/CU).
// This round: erff/expf -> __expf+v_rcp forms (VGPR/LDS-neutral).
// ---------------------------------------------------------------------------
__global__ __launch_bounds__(256, 2) void k_fp(
    const float* __restrict__ x, const __hip_bfloat16* __restrict__ m2g,
    const float* __restrict__ wsM, const float* __restrict__ bp,
    const float* __restrict__ dw, const float* __restrict__ dwb,
    const float* __restrict__ pw1, const float* __restrict__ pw2,
    float* __restrict__ out)
{
    __shared__ __align__(16) char smem[40448];
    unsigned short* xt  = (unsigned short*)smem;            // PE: 12*12*64 (18432B)
    unsigned short* t1  = (unsigned short*)(smem + 18432);  // PE: 10*10*64 (12800B)
    unsigned short* m2s = (unsigned short*)smem;            // F:  144*64   (18432B)
    unsigned short* MtB = (unsigned short*)(smem + 18432);  // F:  4096     (8192B)
    unsigned short* vmL = (unsigned short*)(smem + 31232);  // F:  [64][72] (9216B)
    unsigned short* peL = (unsigned short*)smem;            // F late: [64][72], aliases m2s
    const int tid = threadIdx.x, lane = tid & 63, w = tid >> 6;
    const int quad = lane >> 4, col = lane & 15;
    const int bid = blockIdx.x;
    const int b = bid >> 10, tile = bid & 1023;
    const int y0 = (tile >> 5) * 8, x0 = (tile & 31) * 8;
    const int c = lane;

    // ---------------- Phase PE ----------------
    float w1r[9], w2r[9];
#pragma unroll
    for (int k = 0; k < 9; ++k) { w1r[k] = pw1[c*9+k]; w2r[k] = pw2[c*9+k]; }

    for (int i = tid; i < 12*12*64; i += 256) {
        int yy = i / 768, xx = (i % 768) >> 6;
        int gy = y0 + yy - 2, gx = x0 + xx - 2;
        float v = 0.f;
        if (gy >= 0 && gy < 256 && gx >= 0 && gx < 256)
            v = x[(((size_t)b*256 + gy)*256 + gx)*64 + c];
        xt[i] = f2bf(v);
    }
    __syncthreads();
    for (int i = tid; i < 10*10*64; i += 256) {
        int yy = i / 640, xx = (i % 640) >> 6;
        int gy = y0 + yy - 1, gx = x0 + xx - 1;
        float val = 0.f;
        if (gy >= 0 && gy < 256 && gx >= 0 && gx < 256) {
            float acc = 0.f;
#pragma unroll
            for (int ky = 0; ky < 3; ++ky)
#pragma unroll
                for (int kx = 0; kx < 3; ++kx)
                    acc = fmaf(bf2f(xt[((yy+ky)*12 + xx+kx)*64 + c]),
                               w1r[ky*3+kx], acc);
            val = fast_gelu(acc);
        }
        t1[i] = f2bf(val);
    }
    __syncthreads();

    float pe[4][4];                     // (g,j): px = w*16+g*4+j, channel c
#pragma unroll
    for (int g = 0; g < 4; ++g) {
        const int p0 = w*16 + g*4, py = p0 >> 3, px0 = p0 & 7;
#pragma unroll
        for (int j = 0; j < 4; ++j) {
            float acc = 0.f;
#pragma unroll
            for (int ky = 0; ky < 3; ++ky)
#pragma unroll
                for (int kx = 0; kx < 3; ++kx)
                    acc = fmaf(bf2f(t1[((py+ky)*10 + px0+j+kx)*64 + c]),
                               w2r[ky*3+kx], acc);
            pe[g][j] = acc;
        }
    }
    __syncthreads();                    // PE reads done before LDS realias

    // ---------------- Phase F ----------------
    // Mt as MFMA B-frags: MtB[((ot*2+kh)*64+l)*8+j] = Mt[kh*32+((l>>4)&3)*8+j][ot*16+(l&15)]
    const float* Msrc = wsM + (size_t)b*4096;
    for (int i = tid; i < 4096; i += 256) {
        const int f = i >> 9, l = (i >> 3) & 63, j = i & 7;
        const int ot = f >> 1, kh = f & 1;
        MtB[i] = f2bf(Msrc[(kh*32 + ((l >> 4) & 3)*8 + j)*64 + ot*16 + (l & 15)]);
    }
    for (int i2 = tid; i2 < 2304; i2 += 256) {
        const int pos = i2 >> 4, c4 = (i2 & 15) * 4;
        const int yy = pos / 12, xx = pos - yy*12;
        const int gy = y0 + yy - 2, gx = x0 + xx - 2;
        ushort4 us = make_ushort4(0, 0, 0, 0);
        if (gy >= 0 && gy < 256 && gx >= 0 && gx < 256)
            us = *(const ushort4*)&m2g[(((size_t)b*256 + gy)*256 + gx)*64 + c4];
        *(ushort4*)&m2s[pos*64 + c4] = us;
    }
    __syncthreads();

    const float dwbr = dwb[c];
    float dwr[25];
#pragma unroll
    for (int k = 0; k < 25; ++k) dwr[k] = dw[c*25+k];

#pragma unroll
    for (int g = 0; g < 4; ++g) {
        const int p0 = w*16 + g*4;          // 4 consecutive px in one row
        const int py = p0 >> 3, px0 = p0 & 7;
        float acc[4] = {dwbr, dwbr, dwbr, dwbr};
#pragma unroll
        for (int ky = 0; ky < 5; ++ky) {
            const int rbase = ((py+ky)*12 + px0)*64 + c;
#pragma unroll
            for (int kx8 = 0; kx8 < 8; ++kx8) {
                const float tv = bf2f(m2s[rbase + kx8*64]);
#pragma unroll
                for (int j = 0; j < 4; ++j) {
                    const int kk = kx8 - j;
                    if (kk >= 0 && kk < 5)
                        acc[j] = fmaf(tv, dwr[ky*5 + kk], acc[j]);
                }
            }
        }
#pragma unroll
        for (int j = 0; j < 4; ++j) {
            const size_t P = (size_t)b*65536 + (size_t)(y0+py)*256 + (x0+px0+j);
            const float s = fast_sigmoid(acc[j]);
            vmL[(p0 + j)*72 + c] = f2bf(out[P*64 + c] * (1.f + s));  // vm bf16
        }
    }
    __syncthreads();                    // all m2s reads + vmL writes complete

    // pe -> LDS (aliases dead m2s) in [px][c] layout for C-layout epilogue
#pragma unroll
    for (int g = 0; g < 4; ++g)
#pragma unroll
        for (int j = 0; j < 4; ++j)
            peL[(w*16 + g*4 + j)*72 + c] = f2bf(pe[g][j]);
    __builtin_amdgcn_wave_barrier();
    lds_fence();                        // wave-local peL/vmL visible

    // A-frags: A[m=col(px)][k=quad*8+j+32kh] from vmL
    short8 aV[2];
#pragma unroll
    for (int kh = 0; kh < 2; ++kh)
        aV[kh] = *(const short8*)&vmL[(w*16 + col)*72 + kh*32 + quad*8];
    float bpv[4];
#pragma unroll
    for (int ot = 0; ot < 4; ++ot) bpv[ot] = bp[ot*16 + col];

#pragma unroll
    for (int ot = 0; ot < 4; ++ot) {
        f32x4 a = {0.f, 0.f, 0.f, 0.f};
        a = __builtin_amdgcn_mfma_f32_16x16x32_bf16(aV[0],
                *(const short8*)&MtB[((ot*2+0)*64 + lane)*8], a, 0,0,0);
        a = __builtin_amdgcn_mfma_f32_16x16x32_bf16(aV[1],
                *(const short8*)&MtB[((ot*2+1)*64 + lane)*8], a, 0,0,0);
#pragma unroll
        for (int r = 0; r < 4; ++r) {
            const int pl = w*16 + quad*4 + r;       // C row = px in tile
            const int gy = y0 + (pl >> 3), gx = x0 + (pl & 7);
            out[(((size_t)b*256 + gy)*256 + gx)*64 + ot*16 + col] =
                a[r] + bpv[ot] + bf2f(peL[pl*72 + ot*16 + col]);
        }
    }
}

extern "C" void kernel_launch(void* const* d_in, const int* in_sizes, int n_in,
                              void* d_out, int out_size, void* d_ws, size_t ws_size,
                              hipStream_t stream)
{
    const float* x    = (const float*)d_in[0];
    const float* mask = (const float*)d_in[1];
    const float* Wq   = (const float*)d_in[2];
    const float* Wk   = (const float*)d_in[3];
    const float* Wv   = (const float*)d_in[4];
    const float* resc = (const float*)d_in[5];
    const float* Wp   = (const float*)d_in[6];
    const float* bp   = (const float*)d_in[7];
    const float* mw1  = (const float*)d_in[8];
    const float* mb1  = (const float*)d_in[9];
    const float* mw2  = (const float*)d_in[10];
    const float* mb2  = (const float*)d_in[11];
    const float* mdw  = (const float*)d_in[12];
    const float* mdwb = (const float*)d_in[13];
    const float* pw1  = (const float*)d_in[14];
    const float* pw2  = (const float*)d_in[15];
    float* ws  = (float*)d_ws;
    unsigned short* wg = (unsigned short*)((char*)d_ws + WS_WSWZ_BYTE);
    __hip_bfloat16* m2 = (__hip_bfloat16*)((char*)d_ws + WS_M2_BYTE);
    float* out = (float*)d_out;

    k_prep <<<80,   256, 0, stream>>>(Wq, Wk, Wv, mw1, mw2, wg, ws);
    k_fused<<<512,  256, 0, stream>>>(x, mask, wg, mb1, mb2, ws, out, m2);
    k_attn <<<2,    256, 0, stream>>>(resc, Wp, ws);
    k_fp   <<<2048, 256, 0, stream>>>(x, m2, ws + WS_M, bp, mdw, mdwb,
                                      pw1, pw2, out);
}

// Round 9
// 225.280 us; speedup vs baseline: 1.8751x; 1.2424x over previous
//
#include <hip/hip_runtime.h>
#include <hip/hip_bf16.h>
#include <math.h>

#define BB 2
#define NPIX 131072            // 2*256*256

// ws float header (4-slot accumulators)
#define WS_G    0              // [slot4][B][1024]  (G[c=h*16+d][e])
#define WS_SSQ  8192           // [slot4][2][B][64] (0=q,1=k)
#define WS_M    9216           // [B][4096] ushort: Mt folded, MFMA-B-frag-swizzled
#define WS_WSWZ_BYTE ((size_t)17408*4)            // 20480 ushort pre-swizzled weights (40 KB)
#define WS_M2_BYTE   (WS_WSWZ_BYTE + 40960)       // m2 bf16: NPIX*64*2 = 16.78 MB

typedef __attribute__((ext_vector_type(8))) short short8;
typedef __attribute__((ext_vector_type(4))) float f32x4;

__device__ __forceinline__ unsigned short f2bf(float f) {
    unsigned u = __float_as_uint(f);
    u += 0x7FFFu + ((u >> 16) & 1u);            // RNE
    return (unsigned short)(u >> 16);
}
__device__ __forceinline__ float bf2f(unsigned short s) {
    return __uint_as_float((unsigned)s << 16);
}
__device__ __forceinline__ void lds_fence() {
    __asm__ __volatile__("s_waitcnt lgkmcnt(0)" ::: "memory");
}
// fast transcendentals (r8: erff/expf -> __expf+v_rcp, confirmed −5us on k_fp)
__device__ __forceinline__ float fast_sigmoid(float a) {
    return __builtin_amdgcn_rcpf(1.f + __expf(-a));
}
__device__ __forceinline__ float fast_gelu(float x) {
    float y = 1.5957691216057308f * fmaf(0.044715f * x, x * x, x);
    return x * fast_sigmoid(y);
}

// ---------------------------------------------------------------------------
// K0: pre-swizzle the 5 weight matrices into MFMA B-frag order, bf16, in ws.
// Also zeroes the G/ssq accumulator header (replaces hipMemsetAsync launch).
// ---------------------------------------------------------------------------
__global__ __launch_bounds__(256) void k_prep(const float* __restrict__ Wq,
    const float* __restrict__ Wk, const float* __restrict__ Wv,
    const float* __restrict__ w1, const float* __restrict__ w2,
    unsigned short* __restrict__ wg, float* __restrict__ ws)
{
    const int i = blockIdx.x*256 + threadIdx.x;     // 80 blocks -> 20480
    if (i < 9216) ws[i] = 0.f;                      // zero G + ssq slots
    const int f = i >> 9, l = (i >> 3) & 63, j = i & 7;
    const int matot = f >> 1, kh = f & 1;
    const int mat = matot >> 2, ot = matot & 3;
    const int o = ot*16 + (l & 15);
    const int cc = kh*32 + ((l >> 4) & 3)*8 + j;
    const float* Wsrc[5] = {Wq, Wk, Wv, w1, w2};
    wg[i] = f2bf(Wsrc[mat][o*64 + cc]);
}

// ---------------------------------------------------------------------------
// K1 (MFMA, fused): r0 structure + Gram-via-MFMA (this round).
// q,k now staged TRANSPOSED: S_t[mat][c][24] bf16 (48B rows, 16B-aligned) so
// the Gram frags are single ds_read_b128; G_h = K^T.Q via 4 mfma_16x16x32
// with zero-padded upper K half (replaces ~300 VALU/t scalar loop).
// ssq accumulated from MFMA output regs (no LDS readback, no cvt).
// LDS = 40(wswz) + 24(scr 6KB/wave) + 8(ssq) = 72 KB -> 2 blocks/CU.
// ---------------------------------------------------------------------------
__global__ __launch_bounds__(256, 2) void k_fused(
    const float* __restrict__ x, const float* __restrict__ mask,
    const unsigned short* __restrict__ wg,
    const float* __restrict__ b1, const float* __restrict__ b2,
    float* __restrict__ ws, float* __restrict__ out,
    __hip_bfloat16* __restrict__ m2out)
{
    __shared__ unsigned short wswz[20480];          // 40 KB
    __shared__ unsigned short scr[4][3072];         // 6 KB/wave: S_t [2][64][24]
    __shared__ float s_ssq[4][2][4][64];            // 8 KB [w][mat][ot][lane]
    const int tid = threadIdx.x, lane = tid & 63, w = tid >> 6;
    const int quad = lane >> 4, col = lane & 15;
    const int blk = blockIdx.x, b = blk >> 8, slot = blk & 3;

    for (int i = tid; i < 2560; i += 256)           // 40KB contiguous b128
        ((uint4*)wswz)[i] = ((const uint4*)wg)[i];
    __syncthreads();

    float b1v[4], b2v[4];
#pragma unroll
    for (int ot = 0; ot < 4; ++ot) {
        b1v[ot] = b1[ot*16 + col];
        b2v[ot] = b2[ot*16 + col];
    }

#define WFRAG(matot, kh) (*(const short8*)&wswz[(((matot)*2 + (kh))*64 + lane)*8])

    f32x4 gacc[4];                      // G_h tiles: row d=quad*4+r, col e=lane&15
#pragma unroll
    for (int h = 0; h < 4; ++h) gacc[h] = (f32x4){0.f, 0.f, 0.f, 0.f};
    float ssq[2][4];                    // [mat][ot], channel = ot*16+col
#pragma unroll
    for (int mm = 0; mm < 2; ++mm)
#pragma unroll
        for (int ot = 0; ot < 4; ++ot) ssq[mm][ot] = 0.f;
    const short8 z8 = {0,0,0,0,0,0,0,0};
    unsigned short* S = scr[w];

    for (int t = 0; t < 4; ++t) {
        const int pbase = blk*256 + t*64 + w*16;

        // A-frags from global (fp32 -> bf16): A[m=col(px)][k=quad*8+j (+32kh)]
        short8 xA[2], mA[2];
        {
            const float* xs = x    + ((size_t)(pbase + col))*64 + quad*8;
            const float* ms = mask + ((size_t)(pbase + col))*64 + quad*8;
#pragma unroll
            for (int kh = 0; kh < 2; ++kh) {
                float4 a0 = *(const float4*)(xs + kh*32);
                float4 a1 = *(const float4*)(xs + kh*32 + 4);
                float4 b0 = *(const float4*)(ms + kh*32);
                float4 b1f = *(const float4*)(ms + kh*32 + 4);
#pragma unroll
                for (int j = 0; j < 4; ++j) {
                    xA[kh][j]   = (short)f2bf((&a0.x)[j]);
                    xA[kh][4+j] = (short)f2bf((&a1.x)[j]);
                    mA[kh][j]   = (short)f2bf((&b0.x)[j]);
                    mA[kh][4+j] = (short)f2bf((&b1f.x)[j]);
                }
            }
        }

        // Phase A: q,k -> S_t[mat][c][24] bf16 (transposed), ssq in-register
#pragma unroll
        for (int mm = 0; mm < 2; ++mm) {
#pragma unroll
            for (int ot = 0; ot < 4; ++ot) {
                f32x4 a = {0.f, 0.f, 0.f, 0.f};
                a = __builtin_amdgcn_mfma_f32_16x16x32_bf16(xA[0], WFRAG(mm*4+ot,0), a, 0,0,0);
                a = __builtin_amdgcn_mfma_f32_16x16x32_bf16(xA[1], WFRAG(mm*4+ot,1), a, 0,0,0);
#pragma unroll
                for (int r = 0; r < 4; ++r) {
                    S[mm*1536 + (ot*16 + col)*24 + quad*4 + r] = f2bf(a[r]);
                    ssq[mm][ot] = fmaf(a[r], a[r], ssq[mm][ot]);
                }
            }
        }
        __builtin_amdgcn_wave_barrier();

        // Gram via MFMA: G_h[d][e] += sum_p K[p][h16+d]*Q[p][h16+e]
        // A/B frag: lane(quad,col), elem j: p=(quad&1)*8+j (quads 2,3 zeroed)
        {
            const int gb = (quad & 1) * 8;
#pragma unroll
            for (int h = 0; h < 4; ++h) {
                short8 aq = *(const short8*)&S[(h*16 + col)*24 + gb];
                short8 ak = *(const short8*)&S[1536 + (h*16 + col)*24 + gb];
                if (quad >= 2) { aq = z8; ak = z8; }
                gacc[h] = __builtin_amdgcn_mfma_f32_16x16x32_bf16(ak, aq, gacc[h], 0,0,0);
            }
        }
        lds_fence();                    // Gram reads done before S reused

        // v, m1
        f32x4 vfr[4], m1fr[4];
#pragma unroll
        for (int ot = 0; ot < 4; ++ot) {
            f32x4 a = {0.f, 0.f, 0.f, 0.f};
            a = __builtin_amdgcn_mfma_f32_16x16x32_bf16(xA[0], WFRAG(8+ot,0), a, 0,0,0);
            a = __builtin_amdgcn_mfma_f32_16x16x32_bf16(xA[1], WFRAG(8+ot,1), a, 0,0,0);
            vfr[ot] = a;
        }
#pragma unroll
        for (int ot = 0; ot < 4; ++ot) {
            f32x4 a = {0.f, 0.f, 0.f, 0.f};
            a = __builtin_amdgcn_mfma_f32_16x16x32_bf16(mA[0], WFRAG(12+ot,0), a, 0,0,0);
            a = __builtin_amdgcn_mfma_f32_16x16x32_bf16(mA[1], WFRAG(12+ot,1), a, 0,0,0);
#pragma unroll
            for (int r = 0; r < 4; ++r) a[r] += b1v[ot];
            m1fr[ot] = a;
        }

        // Phase B: vm0 fp32 [16][66] in S, then coalesced 512B row stores
        float* vscr = (float*)S;
#pragma unroll
        for (int ot = 0; ot < 4; ++ot)
#pragma unroll
            for (int r = 0; r < 4; ++r)
                vscr[(quad*4+r)*66 + ot*16 + col] = vfr[ot][r] * m1fr[ot][r];
        __builtin_amdgcn_wave_barrier();
        {
            const int rb = lane >> 5, ci = (lane & 31)*2;
#pragma unroll
            for (int pp = 0; pp < 8; ++pp) {
                const int row = pp*2 + rb;
                float2 v2 = *(const float2*)&vscr[row*66 + ci];
                *(float2*)&out[((size_t)(pbase + row))*64 + ci] = v2;
            }
        }
        lds_fence();                    // vm0 reads done before S reused

        // Phase C: m1 bf16 [16][72] in S -> A-frags for m2
#pragma unroll
        for (int ot = 0; ot < 4; ++ot)
#pragma unroll
            for (int r = 0; r < 4; ++r)
                S[(quad*4+r)*72 + ot*16 + col] = f2bf(m1fr[ot][r]);
        __builtin_amdgcn_wave_barrier();
        short8 a2[2];
#pragma unroll
        for (int kh = 0; kh < 2; ++kh)
            a2[kh] = *(const short8*)&S[col*72 + kh*32 + quad*8];
        lds_fence();                    // a2 reads done before S overwritten

        // Phase D: m2 mfma, bf16 [16][72] in S, coalesced packed-uint stores
#pragma unroll
        for (int ot = 0; ot < 4; ++ot) {
            f32x4 a = {0.f, 0.f, 0.f, 0.f};
            a = __builtin_amdgcn_mfma_f32_16x16x32_bf16(a2[0], WFRAG(16+ot,0), a, 0,0,0);
            a = __builtin_amdgcn_mfma_f32_16x16x32_bf16(a2[1], WFRAG(16+ot,1), a, 0,0,0);
#pragma unroll
            for (int r = 0; r < 4; ++r)
                S[(quad*4+r)*72 + ot*16 + col] = f2bf(a[r] + b2v[ot]);
        }
        __builtin_amdgcn_wave_barrier();
        {
            unsigned short* m2u = (unsigned short*)m2out;
            const int rb = lane >> 5, ci = (lane & 31)*2;
#pragma unroll
            for (int pp = 0; pp < 8; ++pp) {
                const int row = pp*2 + rb;
                unsigned vv = *(const unsigned*)&S[row*72 + ci];
                *(unsigned*)&m2u[((size_t)(pbase + row))*64 + ci] = vv;
            }
        }
        lds_fence();                    // m2 reads done before next iter
    }

    __syncthreads();                    // all waves done with scr

    // two-phase block reduction of G; gr indexed by idx = c*16+e directly
    float* gr = (float*)&scr[0][0];     // 2048 floats (8KB) in 24KB scr
    if (w < 2) {
#pragma unroll
        for (int h = 0; h < 4; ++h)
#pragma unroll
            for (int r = 0; r < 4; ++r)
                gr[w*1024 + (h*16 + quad*4 + r)*16 + col] = gacc[h][r];
    }
#pragma unroll
    for (int mm = 0; mm < 2; ++mm)
#pragma unroll
        for (int ot = 0; ot < 4; ++ot)
            s_ssq[w][mm][ot][lane] = ssq[mm][ot];
    __syncthreads();
    if (w >= 2) {
#pragma unroll
        for (int h = 0; h < 4; ++h)
#pragma unroll
            for (int r = 0; r < 4; ++r)
                gr[(w-2)*1024 + (h*16 + quad*4 + r)*16 + col] += gacc[h][r];
    }
    __syncthreads();
    float* Gg = ws + WS_G + (size_t)slot*2048 + (size_t)b*1024;
    for (int idx = tid; idx < 1024; idx += 256)
        atomicAdd(&Gg[idx], gr[idx] + gr[1024 + idx]);
    if (tid < 128) {
        const int which = tid >> 6, cidx = tid & 63;
        const int ot = cidx >> 4, cl = cidx & 15;
        float s = 0.f;
#pragma unroll
        for (int wv = 0; wv < 4; ++wv)
#pragma unroll
            for (int q = 0; q < 4; ++q)
                s += s_ssq[wv][which][ot][q*16 + cl];
        atomicAdd(ws + WS_SSQ + (size_t)slot*256 + which*128 + b*64 + cidx, s);
    }
#undef WFRAG
}

// ---------------------------------------------------------------------------
// K2: softmax over normalized Gram (sum 4 slots), folded with Wp.
// THIS ROUND: output written as bf16 MFMA-B-frags (k_prep swizzle pattern)
// so k_fp reads frags straight from global (removes its 8KB MtB LDS buffer).
// ---------------------------------------------------------------------------
__global__ __launch_bounds__(256) void k_attn(const float* __restrict__ rescale,
    const float* __restrict__ Wp, float* __restrict__ ws)
{
    __shared__ float sAtt[1024];        // [h][d][e]
    const int b = blockIdx.x, t = threadIdx.x;
    const int d = t >> 4, e = t & 15;
#pragma unroll
    for (int h = 0; h < 4; ++h) {
        float g = 0.f, nk2 = 0.f, nq2 = 0.f;
#pragma unroll
        for (int s = 0; s < 4; ++s) {
            g   += ws[WS_G + s*2048 + b*1024 + (h*16+d)*16 + e];
            nk2 += ws[WS_SSQ + s*256 + 128 + b*64 + h*16 + d];
            nq2 += ws[WS_SSQ + s*256 +   0 + b*64 + h*16 + e];
        }
        float nk = fmaxf(sqrtf(nk2), 1e-12f);
        float nq = fmaxf(sqrtf(nq2), 1e-12f);
        float val = g / (nk*nq) * rescale[h];
        float m = val;
        for (int off = 1; off < 16; off <<= 1) m = fmaxf(m, __shfl_xor(m, off, 16));
        float ev = expf(val - m);
        float s2 = ev;
        for (int off = 1; off < 16; off <<= 1) s2 += __shfl_xor(s2, off, 16);
        sAtt[h*256 + d*16 + e] = ev / s2;
    }
    __syncthreads();
    // Mt[c][o] = sum_d Wp[o][h*16+d]*att[h][d][e(c)], written B-frag-swizzled:
    // i -> f=(ot,kh), l, j ; value Mt[kh*32+((l>>4)&3)*8+j][ot*16+(l&15)]
    unsigned short* Mtw = (unsigned short*)(ws + WS_M) + (size_t)b*4096;
    for (int i = t; i < 4096; i += 256) {
        const int f = i >> 9, l = (i >> 3) & 63, j = i & 7;
        const int ot = f >> 1, kh = f & 1;
        const int o = ot*16 + (l & 15);
        const int cc = kh*32 + ((l >> 4) & 3)*8 + j;
        const int h = cc >> 4, ee = cc & 15;
        float acc = 0.f;
#pragma unroll
        for (int d2 = 0; d2 < 16; ++d2)
            acc = fmaf(Wp[o*64 + h*16 + d2], sAtt[h*256 + d2*16 + ee], acc);
        Mtw[i] = f2bf(acc);
    }
}

// ---------------------------------------------------------------------------
// K3 (merged final+pe, MFMA matmul): per 8x8 tile.
// THIS ROUND: Mt B-frags read from global (L1-hot 16KB, pre-swizzled by
// k_attn) -> LDS drops 40448->31232 B -> 5 blocks/CU (was 4).
// ---------------------------------------------------------------------------
__global__ __launch_bounds__(256, 2) void k_fp(
    const float* __restrict__ x, const __hip_bfloat16* __restrict__ m2g,
    const float* __restrict__ wsM, const float* __restrict__ bp,
    const float* __restrict__ dw, const float* __restrict__ dwb,
    const float* __restrict__ pw1, const float* __restrict__ pw2,
    float* __restrict__ out)
{
    __shared__ __align__(16) char smem[31232];
    unsigned short* xt  = (unsigned short*)smem;            // PE: 12*12*64 (18432B)
    unsigned short* t1  = (unsigned short*)(smem + 18432);  // PE: 10*10*64 (12800B)
    unsigned short* m2s = (unsigned short*)smem;            // F:  144*64   (18432B)
    unsigned short* vmL = (unsigned short*)(smem + 18432);  // F:  [64][72] (9216B)
    unsigned short* peL = (unsigned short*)smem;            // F late: [64][72], aliases m2s
    const int tid = threadIdx.x, lane = tid & 63, w = tid >> 6;
    const int quad = lane >> 4, col = lane & 15;
    const int bid = blockIdx.x;
    const int b = bid >> 10, tile = bid & 1023;
    const int y0 = (tile >> 5) * 8, x0 = (tile & 31) * 8;
    const int c = lane;

    // ---------------- Phase PE ----------------
    float w1r[9], w2r[9];
#pragma unroll
    for (int k = 0; k < 9; ++k) { w1r[k] = pw1[c*9+k]; w2r[k] = pw2[c*9+k]; }

    for (int i = tid; i < 12*12*64; i += 256) {
        int yy = i / 768, xx = (i % 768) >> 6;
        int gy = y0 + yy - 2, gx = x0 + xx - 2;
        float v = 0.f;
        if (gy >= 0 && gy < 256 && gx >= 0 && gx < 256)
            v = x[(((size_t)b*256 + gy)*256 + gx)*64 + c];
        xt[i] = f2bf(v);
    }
    __syncthreads();
    for (int i = tid; i < 10*10*64; i += 256) {
        int yy = i / 640, xx = (i % 640) >> 6;
        int gy = y0 + yy - 1, gx = x0 + xx - 1;
        float val = 0.f;
        if (gy >= 0 && gy < 256 && gx >= 0 && gx < 256) {
            float acc = 0.f;
#pragma unroll
            for (int ky = 0; ky < 3; ++ky)
#pragma unroll
                for (int kx = 0; kx < 3; ++kx)
                    acc = fmaf(bf2f(xt[((yy+ky)*12 + xx+kx)*64 + c]),
                               w1r[ky*3+kx], acc);
            val = fast_gelu(acc);
        }
        t1[i] = f2bf(val);
    }
    __syncthreads();

    float pe[4][4];                     // (g,j): px = w*16+g*4+j, channel c
#pragma unroll
    for (int g = 0; g < 4; ++g) {
        const int p0 = w*16 + g*4, py = p0 >> 3, px0 = p0 & 7;
#pragma unroll
        for (int j = 0; j < 4; ++j) {
            float acc = 0.f;
#pragma unroll
            for (int ky = 0; ky < 3; ++ky)
#pragma unroll
                for (int kx = 0; kx < 3; ++kx)
                    acc = fmaf(bf2f(t1[((py+ky)*10 + px0+j+kx)*64 + c]),
                               w2r[ky*3+kx], acc);
            pe[g][j] = acc;
        }
    }
    __syncthreads();                    // PE reads done before LDS realias

    // ---------------- Phase F ----------------
    for (int i2 = tid; i2 < 2304; i2 += 256) {
        const int pos = i2 >> 4, c4 = (i2 & 15) * 4;
        const int yy = pos / 12, xx = pos - yy*12;
        const int gy = y0 + yy - 2, gx = x0 + xx - 2;
        ushort4 us = make_ushort4(0, 0, 0, 0);
        if (gy >= 0 && gy < 256 && gx >= 0 && gx < 256)
            us = *(const ushort4*)&m2g[(((size_t)b*256 + gy)*256 + gx)*64 + c4];
        *(ushort4*)&m2s[pos*64 + c4] = us;
    }
    __syncthreads();

    const float dwbr = dwb[c];
    float dwr[25];
#pragma unroll
    for (int k = 0; k < 25; ++k) dwr[k] = dw[c*25+k];

#pragma unroll
    for (int g = 0; g < 4; ++g) {
        const int p0 = w*16 + g*4;          // 4 consecutive px in one row
        const int py = p0 >> 3, px0 = p0 & 7;
        float acc[4] = {dwbr, dwbr, dwbr, dwbr};
#pragma unroll
        for (int ky = 0; ky < 5; ++ky) {
            const int rbase = ((py+ky)*12 + px0)*64 + c;
#pragma unroll
            for (int kx8 = 0; kx8 < 8; ++kx8) {
                const float tv = bf2f(m2s[rbase + kx8*64]);
#pragma unroll
                for (int j = 0; j < 4; ++j) {
                    const int kk = kx8 - j;
                    if (kk >= 0 && kk < 5)
                        acc[j] = fmaf(tv, dwr[ky*5 + kk], acc[j]);
                }
            }
        }
#pragma unroll
        for (int j = 0; j < 4; ++j) {
            const size_t P = (size_t)b*65536 + (size_t)(y0+py)*256 + (x0+px0+j);
            const float s = fast_sigmoid(acc[j]);
            vmL[(p0 + j)*72 + c] = f2bf(out[P*64 + c] * (1.f + s));  // vm bf16
        }
    }
    __syncthreads();                    // all m2s reads + vmL writes complete

    // pe -> LDS (aliases dead m2s) in [px][c] layout for C-layout epilogue
#pragma unroll
    for (int g = 0; g < 4; ++g)
#pragma unroll
        for (int j = 0; j < 4; ++j)
            peL[(w*16 + g*4 + j)*72 + c] = f2bf(pe[g][j]);
    __builtin_amdgcn_wave_barrier();
    lds_fence();                        // wave-local peL/vmL visible

    // A-frags: A[m=col(px)][k=quad*8+j+32kh] from vmL
    short8 aV[2];
#pragma unroll
    for (int kh = 0; kh < 2; ++kh)
        aV[kh] = *(const short8*)&vmL[(w*16 + col)*72 + kh*32 + quad*8];
    float bpv[4];
#pragma unroll
    for (int ot = 0; ot < 4; ++ot) bpv[ot] = bp[ot*16 + col];

    const unsigned short* Mtw = (const unsigned short*)wsM + (size_t)b*4096;
#pragma unroll
    for (int ot = 0; ot < 4; ++ot) {
        short8 m0 = *(const short8*)&Mtw[((ot*2+0)*64 + lane)*8];
        short8 m1f = *(const short8*)&Mtw[((ot*2+1)*64 + lane)*8];
        f32x4 a = {0.f, 0.f, 0.f, 0.f};
        a = __builtin_amdgcn_mfma_f32_16x16x32_bf16(aV[0], m0, a, 0,0,0);
        a = __builtin_amdgcn_mfma_f32_16x16x32_bf16(aV[1], m1f, a, 0,0,0);
#pragma unroll
        for (int r = 0; r < 4; ++r) {
            const int pl = w*16 + quad*4 + r;       // C row = px in tile
            const int gy = y0 + (pl >> 3), gx = x0 + (pl & 7);
            out[(((size_t)b*256 + gy)*256 + gx)*64 + ot*16 + col] =
                a[r] + bpv[ot] + bf2f(peL[pl*72 + ot*16 + col]);
        }
    }
}

extern "C" void kernel_launch(void* const* d_in, const int* in_sizes, int n_in,
                              void* d_out, int out_size, void* d_ws, size_t ws_size,
                              hipStream_t stream)
{
    const float* x    = (const float*)d_in[0];
    const float* mask = (const float*)d_in[1];
    const float* Wq   = (const float*)d_in[2];
    const float* Wk   = (const float*)d_in[3];
    const float* Wv   = (const float*)d_in[4];
    const float* resc = (const float*)d_in[5];
    const float* Wp   = (const float*)d_in[6];
    const float* bp   = (const float*)d_in[7];
    const float* mw1  = (const float*)d_in[8];
    const float* mb1  = (const float*)d_in[9];
    const float* mw2  = (const float*)d_in[10];
    const float* mb2  = (const float*)d_in[11];
    const float* mdw  = (const float*)d_in[12];
    const float* mdwb = (const float*)d_in[13];
    const float* pw1  = (const float*)d_in[14];
    const float* pw2  = (const float*)d_in[15];
    float* ws  = (float*)d_ws;
    unsigned short* wg = (unsigned short*)((char*)d_ws + WS_WSWZ_BYTE);
    __hip_bfloat16* m2 = (__hip_bfloat16*)((char*)d_ws + WS_M2_BYTE);
    float* out = (float*)d_out;

    k_prep <<<80,   256, 0, stream>>>(Wq, Wk, Wv, mw1, mw2, wg, ws);
    k_fused<<<512,  256, 0, stream>>>(x, mask, wg, mb1, mb2, ws, out, m2);
    k_attn <<<2,    256, 0, stream>>>(resc, Wp, ws);
    k_fp   <<<2048, 256, 0, stream>>>(x, m2, ws + WS_M, bp, mdw, mdwb,
                                      pw1, pw2, out);
}

// Round 10
// 215.384 us; speedup vs baseline: 1.9612x; 1.0459x over previous
//
#include <hip/hip_runtime.h>
#include <hip/hip_bf16.h>
#include <math.h>

#define BB 2
#define NPIX 131072            // 2*256*256

// ws float header (4-slot accumulators)
#define WS_G    0              // [slot4][B][1024]  (G[c=h*16+d][e])
#define WS_SSQ  8192           // [slot4][2][B][64] (0=q,1=k)
#define WS_M    9216           // [B][4096] ushort: Mt folded, MFMA-B-frag-swizzled
#define WS_WSWZ_BYTE ((size_t)17408*4)            // 20480 ushort pre-swizzled weights (40 KB)
#define WS_M2_BYTE   (WS_WSWZ_BYTE + 40960)       // m2 bf16: NPIX*64*2 = 16.78 MB

typedef __attribute__((ext_vector_type(8))) short short8;
typedef __attribute__((ext_vector_type(4))) float f32x4;

__device__ __forceinline__ unsigned short f2bf(float f) {
    unsigned u = __float_as_uint(f);
    u += 0x7FFFu + ((u >> 16) & 1u);            // RNE
    return (unsigned short)(u >> 16);
}
__device__ __forceinline__ float bf2f(unsigned short s) {
    return __uint_as_float((unsigned)s << 16);
}
__device__ __forceinline__ void lds_fence() {
    __asm__ __volatile__("s_waitcnt lgkmcnt(0)" ::: "memory");
}
// fast transcendentals (r8: erff/expf -> __expf+v_rcp, confirmed −5us on k_fp)
__device__ __forceinline__ float fast_sigmoid(float a) {
    return __builtin_amdgcn_rcpf(1.f + __expf(-a));
}
__device__ __forceinline__ float fast_gelu(float x) {
    float y = 1.5957691216057308f * fmaf(0.044715f * x, x * x, x);
    return x * fast_sigmoid(y);
}

// ---------------------------------------------------------------------------
// K0: pre-swizzle the 5 weight matrices into MFMA B-frag order, bf16, in ws.
// Also zeroes the G/ssq accumulator header (replaces hipMemsetAsync launch).
// ---------------------------------------------------------------------------
__global__ __launch_bounds__(256) void k_prep(const float* __restrict__ Wq,
    const float* __restrict__ Wk, const float* __restrict__ Wv,
    const float* __restrict__ w1, const float* __restrict__ w2,
    unsigned short* __restrict__ wg, float* __restrict__ ws)
{
    const int i = blockIdx.x*256 + threadIdx.x;     // 80 blocks -> 20480
    if (i < 9216) ws[i] = 0.f;                      // zero G + ssq slots
    const int f = i >> 9, l = (i >> 3) & 63, j = i & 7;
    const int matot = f >> 1, kh = f & 1;
    const int mat = matot >> 2, ot = matot & 3;
    const int o = ot*16 + (l & 15);
    const int cc = kh*32 + ((l >> 4) & 3)*8 + j;
    const float* Wsrc[5] = {Wq, Wk, Wv, w1, w2};
    wg[i] = f2bf(Wsrc[mat][o*64 + cc]);
}

// ---------------------------------------------------------------------------
// K1 (MFMA, fused): r0 structure + Gram-via-MFMA (r9, confirmed big win).
// q,k staged TRANSPOSED: S_t[mat][c][24] bf16; G_h = K^T.Q via 4 mfma with
// zero-padded upper K half. ssq accumulated from MFMA output regs.
// LDS = 40(wswz) + 24(scr 6KB/wave) + 8(ssq) = 72 KB -> 2 blocks/CU.
// ---------------------------------------------------------------------------
__global__ __launch_bounds__(256, 2) void k_fused(
    const float* __restrict__ x, const float* __restrict__ mask,
    const unsigned short* __restrict__ wg,
    const float* __restrict__ b1, const float* __restrict__ b2,
    float* __restrict__ ws, float* __restrict__ out,
    __hip_bfloat16* __restrict__ m2out)
{
    __shared__ unsigned short wswz[20480];          // 40 KB
    __shared__ unsigned short scr[4][3072];         // 6 KB/wave: S_t [2][64][24]
    __shared__ float s_ssq[4][2][4][64];            // 8 KB [w][mat][ot][lane]
    const int tid = threadIdx.x, lane = tid & 63, w = tid >> 6;
    const int quad = lane >> 4, col = lane & 15;
    const int blk = blockIdx.x, b = blk >> 8, slot = blk & 3;

    for (int i = tid; i < 2560; i += 256)           // 40KB contiguous b128
        ((uint4*)wswz)[i] = ((const uint4*)wg)[i];
    __syncthreads();

    float b1v[4], b2v[4];
#pragma unroll
    for (int ot = 0; ot < 4; ++ot) {
        b1v[ot] = b1[ot*16 + col];
        b2v[ot] = b2[ot*16 + col];
    }

#define WFRAG(matot, kh) (*(const short8*)&wswz[(((matot)*2 + (kh))*64 + lane)*8])

    f32x4 gacc[4];                      // G_h tiles: row d=quad*4+r, col e=lane&15
#pragma unroll
    for (int h = 0; h < 4; ++h) gacc[h] = (f32x4){0.f, 0.f, 0.f, 0.f};
    float ssq[2][4];                    // [mat][ot], channel = ot*16+col
#pragma unroll
    for (int mm = 0; mm < 2; ++mm)
#pragma unroll
        for (int ot = 0; ot < 4; ++ot) ssq[mm][ot] = 0.f;
    const short8 z8 = {0,0,0,0,0,0,0,0};
    unsigned short* S = scr[w];

    for (int t = 0; t < 4; ++t) {
        const int pbase = blk*256 + t*64 + w*16;

        // A-frags from global (fp32 -> bf16): A[m=col(px)][k=quad*8+j (+32kh)]
        short8 xA[2], mA[2];
        {
            const float* xs = x    + ((size_t)(pbase + col))*64 + quad*8;
            const float* ms = mask + ((size_t)(pbase + col))*64 + quad*8;
#pragma unroll
            for (int kh = 0; kh < 2; ++kh) {
                float4 a0 = *(const float4*)(xs + kh*32);
                float4 a1 = *(const float4*)(xs + kh*32 + 4);
                float4 b0 = *(const float4*)(ms + kh*32);
                float4 b1f = *(const float4*)(ms + kh*32 + 4);
#pragma unroll
                for (int j = 0; j < 4; ++j) {
                    xA[kh][j]   = (short)f2bf((&a0.x)[j]);
                    xA[kh][4+j] = (short)f2bf((&a1.x)[j]);
                    mA[kh][j]   = (short)f2bf((&b0.x)[j]);
                    mA[kh][4+j] = (short)f2bf((&b1f.x)[j]);
                }
            }
        }

        // Phase A: q,k -> S_t[mat][c][24] bf16 (transposed), ssq in-register
#pragma unroll
        for (int mm = 0; mm < 2; ++mm) {
#pragma unroll
            for (int ot = 0; ot < 4; ++ot) {
                f32x4 a = {0.f, 0.f, 0.f, 0.f};
                a = __builtin_amdgcn_mfma_f32_16x16x32_bf16(xA[0], WFRAG(mm*4+ot,0), a, 0,0,0);
                a = __builtin_amdgcn_mfma_f32_16x16x32_bf16(xA[1], WFRAG(mm*4+ot,1), a, 0,0,0);
#pragma unroll
                for (int r = 0; r < 4; ++r) {
                    S[mm*1536 + (ot*16 + col)*24 + quad*4 + r] = f2bf(a[r]);
                    ssq[mm][ot] = fmaf(a[r], a[r], ssq[mm][ot]);
                }
            }
        }
        __builtin_amdgcn_wave_barrier();

        // Gram via MFMA: G_h[d][e] += sum_p K[p][h16+d]*Q[p][h16+e]
        // A/B frag: lane(quad,col), elem j: p=(quad&1)*8+j (quads 2,3 zeroed)
        {
            const int gb = (quad & 1) * 8;
#pragma unroll
            for (int h = 0; h < 4; ++h) {
                short8 aq = *(const short8*)&S[(h*16 + col)*24 + gb];
                short8 ak = *(const short8*)&S[1536 + (h*16 + col)*24 + gb];
                if (quad >= 2) { aq = z8; ak = z8; }
                gacc[h] = __builtin_amdgcn_mfma_f32_16x16x32_bf16(ak, aq, gacc[h], 0,0,0);
            }
        }
        lds_fence();                    // Gram reads done before S reused

        // v, m1
        f32x4 vfr[4], m1fr[4];
#pragma unroll
        for (int ot = 0; ot < 4; ++ot) {
            f32x4 a = {0.f, 0.f, 0.f, 0.f};
            a = __builtin_amdgcn_mfma_f32_16x16x32_bf16(xA[0], WFRAG(8+ot,0), a, 0,0,0);
            a = __builtin_amdgcn_mfma_f32_16x16x32_bf16(xA[1], WFRAG(8+ot,1), a, 0,0,0);
            vfr[ot] = a;
        }
#pragma unroll
        for (int ot = 0; ot < 4; ++ot) {
            f32x4 a = {0.f, 0.f, 0.f, 0.f};
            a = __builtin_amdgcn_mfma_f32_16x16x32_bf16(mA[0], WFRAG(12+ot,0), a, 0,0,0);
            a = __builtin_amdgcn_mfma_f32_16x16x32_bf16(mA[1], WFRAG(12+ot,1), a, 0,0,0);
#pragma unroll
            for (int r = 0; r < 4; ++r) a[r] += b1v[ot];
            m1fr[ot] = a;
        }

        // Phase B: vm0 fp32 [16][66] in S, then coalesced 512B row stores
        float* vscr = (float*)S;
#pragma unroll
        for (int ot = 0; ot < 4; ++ot)
#pragma unroll
            for (int r = 0; r < 4; ++r)
                vscr[(quad*4+r)*66 + ot*16 + col] = vfr[ot][r] * m1fr[ot][r];
        __builtin_amdgcn_wave_barrier();
        {
            const int rb = lane >> 5, ci = (lane & 31)*2;
#pragma unroll
            for (int pp = 0; pp < 8; ++pp) {
                const int row = pp*2 + rb;
                float2 v2 = *(const float2*)&vscr[row*66 + ci];
                *(float2*)&out[((size_t)(pbase + row))*64 + ci] = v2;
            }
        }
        lds_fence();                    // vm0 reads done before S reused

        // Phase C: m1 bf16 [16][72] in S -> A-frags for m2
#pragma unroll
        for (int ot = 0; ot < 4; ++ot)
#pragma unroll
            for (int r = 0; r < 4; ++r)
                S[(quad*4+r)*72 + ot*16 + col] = f2bf(m1fr[ot][r]);
        __builtin_amdgcn_wave_barrier();
        short8 a2[2];
#pragma unroll
        for (int kh = 0; kh < 2; ++kh)
            a2[kh] = *(const short8*)&S[col*72 + kh*32 + quad*8];
        lds_fence();                    // a2 reads done before S overwritten

        // Phase D: m2 mfma, bf16 [16][72] in S, coalesced packed-uint stores
#pragma unroll
        for (int ot = 0; ot < 4; ++ot) {
            f32x4 a = {0.f, 0.f, 0.f, 0.f};
            a = __builtin_amdgcn_mfma_f32_16x16x32_bf16(a2[0], WFRAG(16+ot,0), a, 0,0,0);
            a = __builtin_amdgcn_mfma_f32_16x16x32_bf16(a2[1], WFRAG(16+ot,1), a, 0,0,0);
#pragma unroll
            for (int r = 0; r < 4; ++r)
                S[(quad*4+r)*72 + ot*16 + col] = f2bf(a[r] + b2v[ot]);
        }
        __builtin_amdgcn_wave_barrier();
        {
            unsigned short* m2u = (unsigned short*)m2out;
            const int rb = lane >> 5, ci = (lane & 31)*2;
#pragma unroll
            for (int pp = 0; pp < 8; ++pp) {
                const int row = pp*2 + rb;
                unsigned vv = *(const unsigned*)&S[row*72 + ci];
                *(unsigned*)&m2u[((size_t)(pbase + row))*64 + ci] = vv;
            }
        }
        lds_fence();                    // m2 reads done before next iter
    }

    __syncthreads();                    // all waves done with scr

    // two-phase block reduction of G; gr indexed by idx = c*16+e directly
    float* gr = (float*)&scr[0][0];     // 2048 floats (8KB) in 24KB scr
    if (w < 2) {
#pragma unroll
        for (int h = 0; h < 4; ++h)
#pragma unroll
            for (int r = 0; r < 4; ++r)
                gr[w*1024 + (h*16 + quad*4 + r)*16 + col] = gacc[h][r];
    }
#pragma unroll
    for (int mm = 0; mm < 2; ++mm)
#pragma unroll
        for (int ot = 0; ot < 4; ++ot)
            s_ssq[w][mm][ot][lane] = ssq[mm][ot];
    __syncthreads();
    if (w >= 2) {
#pragma unroll
        for (int h = 0; h < 4; ++h)
#pragma unroll
            for (int r = 0; r < 4; ++r)
                gr[(w-2)*1024 + (h*16 + quad*4 + r)*16 + col] += gacc[h][r];
    }
    __syncthreads();
    float* Gg = ws + WS_G + (size_t)slot*2048 + (size_t)b*1024;
    for (int idx = tid; idx < 1024; idx += 256)
        atomicAdd(&Gg[idx], gr[idx] + gr[1024 + idx]);
    if (tid < 128) {
        const int which = tid >> 6, cidx = tid & 63;
        const int ot = cidx >> 4, cl = cidx & 15;
        float s = 0.f;
#pragma unroll
        for (int wv = 0; wv < 4; ++wv)
#pragma unroll
            for (int q = 0; q < 4; ++q)
                s += s_ssq[wv][which][ot][q*16 + cl];
        atomicAdd(ws + WS_SSQ + (size_t)slot*256 + which*128 + b*64 + cidx, s);
    }
#undef WFRAG
}

// ---------------------------------------------------------------------------
// K2: softmax over normalized Gram (sum 4 slots), folded with Wp.
// Output written as bf16 MFMA-B-frags so k_fp reads frags from global.
// ---------------------------------------------------------------------------
__global__ __launch_bounds__(256) void k_attn(const float* __restrict__ rescale,
    const float* __restrict__ Wp, float* __restrict__ ws)
{
    __shared__ float sAtt[1024];        // [h][d][e]
    const int b = blockIdx.x, t = threadIdx.x;
    const int d = t >> 4, e = t & 15;
#pragma unroll
    for (int h = 0; h < 4; ++h) {
        float g = 0.f, nk2 = 0.f, nq2 = 0.f;
#pragma unroll
        for (int s = 0; s < 4; ++s) {
            g   += ws[WS_G + s*2048 + b*1024 + (h*16+d)*16 + e];
            nk2 += ws[WS_SSQ + s*256 + 128 + b*64 + h*16 + d];
            nq2 += ws[WS_SSQ + s*256 +   0 + b*64 + h*16 + e];
        }
        float nk = fmaxf(sqrtf(nk2), 1e-12f);
        float nq = fmaxf(sqrtf(nq2), 1e-12f);
        float val = g / (nk*nq) * rescale[h];
        float m = val;
        for (int off = 1; off < 16; off <<= 1) m = fmaxf(m, __shfl_xor(m, off, 16));
        float ev = expf(val - m);
        float s2 = ev;
        for (int off = 1; off < 16; off <<= 1) s2 += __shfl_xor(s2, off, 16);
        sAtt[h*256 + d*16 + e] = ev / s2;
    }
    __syncthreads();
    // Mt[c][o] = sum_d Wp[o][h*16+d]*att[h][d][e(c)], written B-frag-swizzled
    unsigned short* Mtw = (unsigned short*)(ws + WS_M) + (size_t)b*4096;
    for (int i = t; i < 4096; i += 256) {
        const int f = i >> 9, l = (i >> 3) & 63, j = i & 7;
        const int ot = f >> 1, kh = f & 1;
        const int o = ot*16 + (l & 15);
        const int cc = kh*32 + ((l >> 4) & 3)*8 + j;
        const int h = cc >> 4, ee = cc & 15;
        float acc = 0.f;
#pragma unroll
        for (int d2 = 0; d2 < 16; ++d2)
            acc = fmaf(Wp[o*64 + h*16 + d2], sAtt[h*256 + d2*16 + ee], acc);
        Mtw[i] = f2bf(acc);
    }
}

// ---------------------------------------------------------------------------
// K3 (merged final+pe, MFMA matmul): per 8x8 tile.
// r9: VGPR 68 -> 4 waves/SIMD (4 blk/CU); LDS 31232 allows 5 blk/CU.
// THIS ROUND: pe[4][4] f32 (16 VGPR) -> bf16-packed peP[4][2] (8 VGPR;
// bit-identical, peL stored bf16 anyway) + __launch_bounds__(256,4) so the
// allocator targets the 64-VGPR budget -> 8 waves/SIMD cap, 5 blk/CU.
// Spill canary: FETCH must stay ~53MB (r1/r2 lesson).
// ---------------------------------------------------------------------------
__global__ __launch_bounds__(256, 4) void k_fp(
    const float* __restrict__ x, const __hip_bfloat16* __restrict__ m2g,
    const float* __restrict__ wsM, const float* __restrict__ bp,
    const float* __restrict__ dw, const float* __restrict__ dwb,
    const float* __restrict__ pw1, const float* __restrict__ pw2,
    float* __restrict__ out)
{
    __shared__ __align__(16) char smem[31232];
    unsigned short* xt  = (unsigned short*)smem;            // PE: 12*12*64 (18432B)
    unsigned short* t1  = (unsigned short*)(smem + 18432);  // PE: 10*10*64 (12800B)
    unsigned short* m2s = (unsigned short*)smem;            // F:  144*64   (18432B)
    unsigned short* vmL = (unsigned short*)(smem + 18432);  // F:  [64][72] (9216B)
    unsigned short* peL = (unsigned short*)smem;            // F late: [64][72], aliases m2s
    const int tid = threadIdx.x, lane = tid & 63, w = tid >> 6;
    const int quad = lane >> 4, col = lane & 15;
    const int bid = blockIdx.x;
    const int b = bid >> 10, tile = bid & 1023;
    const int y0 = (tile >> 5) * 8, x0 = (tile & 31) * 8;
    const int c = lane;

    // ---------------- Phase PE ----------------
    float w1r[9], w2r[9];
#pragma unroll
    for (int k = 0; k < 9; ++k) { w1r[k] = pw1[c*9+k]; w2r[k] = pw2[c*9+k]; }

    for (int i = tid; i < 12*12*64; i += 256) {
        int yy = i / 768, xx = (i % 768) >> 6;
        int gy = y0 + yy - 2, gx = x0 + xx - 2;
        float v = 0.f;
        if (gy >= 0 && gy < 256 && gx >= 0 && gx < 256)
            v = x[(((size_t)b*256 + gy)*256 + gx)*64 + c];
        xt[i] = f2bf(v);
    }
    __syncthreads();
    for (int i = tid; i < 10*10*64; i += 256) {
        int yy = i / 640, xx = (i % 640) >> 6;
        int gy = y0 + yy - 1, gx = x0 + xx - 1;
        float val = 0.f;
        if (gy >= 0 && gy < 256 && gx >= 0 && gx < 256) {
            float acc = 0.f;
#pragma unroll
            for (int ky = 0; ky < 3; ++ky)
#pragma unroll
                for (int kx = 0; kx < 3; ++kx)
                    acc = fmaf(bf2f(xt[((yy+ky)*12 + xx+kx)*64 + c]),
                               w1r[ky*3+kx], acc);
            val = fast_gelu(acc);
        }
        t1[i] = f2bf(val);
    }
    __syncthreads();

    unsigned peP[4][2];                 // pe bf16-packed: (g, j/2) -> lo=j0 hi=j1
#pragma unroll
    for (int g = 0; g < 4; ++g) {
        const int p0 = w*16 + g*4, py = p0 >> 3, px0 = p0 & 7;
#pragma unroll
        for (int j2 = 0; j2 < 2; ++j2) {
            unsigned pk = 0;
#pragma unroll
            for (int jj = 0; jj < 2; ++jj) {
                const int j = j2*2 + jj;
                float acc = 0.f;
#pragma unroll
                for (int ky = 0; ky < 3; ++ky)
#pragma unroll
                    for (int kx = 0; kx < 3; ++kx)
                        acc = fmaf(bf2f(t1[((py+ky)*10 + px0+j+kx)*64 + c]),
                                   w2r[ky*3+kx], acc);
                pk |= (unsigned)f2bf(acc) << (jj*16);
            }
            peP[g][j2] = pk;
        }
    }
    __syncthreads();                    // PE reads done before LDS realias

    // ---------------- Phase F ----------------
    for (int i2 = tid; i2 < 2304; i2 += 256) {
        const int pos = i2 >> 4, c4 = (i2 & 15) * 4;
        const int yy = pos / 12, xx = pos - yy*12;
        const int gy = y0 + yy - 2, gx = x0 + xx - 2;
        ushort4 us = make_ushort4(0, 0, 0, 0);
        if (gy >= 0 && gy < 256 && gx >= 0 && gx < 256)
            us = *(const ushort4*)&m2g[(((size_t)b*256 + gy)*256 + gx)*64 + c4];
        *(ushort4*)&m2s[pos*64 + c4] = us;
    }
    __syncthreads();

    const float dwbr = dwb[c];
    float dwr[25];
#pragma unroll
    for (int k = 0; k < 25; ++k) dwr[k] = dw[c*25+k];

#pragma unroll
    for (int g = 0; g < 4; ++g) {
        const int p0 = w*16 + g*4;          // 4 consecutive px in one row
        const int py = p0 >> 3, px0 = p0 & 7;
        float acc[4] = {dwbr, dwbr, dwbr, dwbr};
#pragma unroll
        for (int ky = 0; ky < 5; ++ky) {
            const int rbase = ((py+ky)*12 + px0)*64 + c;
#pragma unroll
            for (int kx8 = 0; kx8 < 8; ++kx8) {
                const float tv = bf2f(m2s[rbase + kx8*64]);
#pragma unroll
                for (int j = 0; j < 4; ++j) {
                    const int kk = kx8 - j;
                    if (kk >= 0 && kk < 5)
                        acc[j] = fmaf(tv, dwr[ky*5 + kk], acc[j]);
                }
            }
        }
#pragma unroll
        for (int j = 0; j < 4; ++j) {
            const size_t P = (size_t)b*65536 + (size_t)(y0+py)*256 + (x0+px0+j);
            const float s = fast_sigmoid(acc[j]);
            vmL[(p0 + j)*72 + c] = f2bf(out[P*64 + c] * (1.f + s));  // vm bf16
        }
    }
    __syncthreads();                    // all m2s reads + vmL writes complete

    // pe -> LDS (aliases dead m2s) in [px][c] layout for C-layout epilogue
#pragma unroll
    for (int g = 0; g < 4; ++g)
#pragma unroll
        for (int j = 0; j < 4; ++j)
            peL[(w*16 + g*4 + j)*72 + c] =
                (unsigned short)(peP[g][j >> 1] >> ((j & 1)*16));
    __builtin_amdgcn_wave_barrier();
    lds_fence();                        // wave-local peL/vmL visible

    // A-frags: A[m=col(px)][k=quad*8+j+32kh] from vmL
    short8 aV[2];
#pragma unroll
    for (int kh = 0; kh < 2; ++kh)
        aV[kh] = *(const short8*)&vmL[(w*16 + col)*72 + kh*32 + quad*8];
    float bpv[4];
#pragma unroll
    for (int ot = 0; ot < 4; ++ot) bpv[ot] = bp[ot*16 + col];

    const unsigned short* Mtw = (const unsigned short*)wsM + (size_t)b*4096;
#pragma unroll
    for (int ot = 0; ot < 4; ++ot) {
        short8 m0 = *(const short8*)&Mtw[((ot*2+0)*64 + lane)*8];
        short8 m1f = *(const short8*)&Mtw[((ot*2+1)*64 + lane)*8];
        f32x4 a = {0.f, 0.f, 0.f, 0.f};
        a = __builtin_amdgcn_mfma_f32_16x16x32_bf16(aV[0], m0, a, 0,0,0);
        a = __builtin_amdgcn_mfma_f32_16x16x32_bf16(aV[1], m1f, a, 0,0,0);
#pragma unroll
        for (int r = 0; r < 4; ++r) {
            const int pl = w*16 + quad*4 + r;       // C row = px in tile
            const int gy = y0 + (pl >> 3), gx = x0 + (pl & 7);
            out[(((size_t)b*256 + gy)*256 + gx)*64 + ot*16 + col] =
                a[r] + bpv[ot] + bf2f(peL[pl*72 + ot*16 + col]);
        }
    }
}

extern "C" void kernel_launch(void* const* d_in, const int* in_sizes, int n_in,
                              void* d_out, int out_size, void* d_ws, size_t ws_size,
                              hipStream_t stream)
{
    const float* x    = (const float*)d_in[0];
    const float* mask = (const float*)d_in[1];
    const float* Wq   = (const float*)d_in[2];
    const float* Wk   = (const float*)d_in[3];
    const float* Wv   = (const float*)d_in[4];
    const float* resc = (const float*)d_in[5];
    const float* Wp   = (const float*)d_in[6];
    const float* bp   = (const float*)d_in[7];
    const float* mw1  = (const float*)d_in[8];
    const float* mb1  = (const float*)d_in[9];
    const float* mw2  = (const float*)d_in[10];
    const float* mb2  = (const float*)d_in[11];
    const float* mdw  = (const float*)d_in[12];
    const float* mdwb = (const float*)d_in[13];
    const float* pw1  = (const float*)d_in[14];
    const float* pw2  = (const float*)d_in[15];
    float* ws  = (float*)d_ws;
    unsigned short* wg = (unsigned short*)((char*)d_ws + WS_WSWZ_BYTE);
    __hip_bfloat16* m2 = (__hip_bfloat16*)((char*)d_ws + WS_M2_BYTE);
    float* out = (float*)d_out;

    k_prep <<<80,   256, 0, stream>>>(Wq, Wk, Wv, mw1, mw2, wg, ws);
    k_fused<<<512,  256, 0, stream>>>(x, mask, wg, mb1, mb2, ws, out, m2);
    k_attn <<<2,    256, 0, stream>>>(resc, Wp, ws);
    k_fp   <<<2048, 256, 0, stream>>>(x, m2, ws + WS_M, bp, mdw, mdwb,
                                      pw1, pw2, out);
}